// Round 3
// baseline (327.379 us; speedup 1.0000x reference)
//
#include <hip/hip_runtime.h>

#define BN_EPS 1e-5f

// ---------------------------------------------------------------------------
// Depthwise 3x3 conv, SAME padding, stride 1. One block per (b,c) plane.
// HW = plane side, LOGW = log2(HW), NITER = HW*HW/256, CMASK = C-1.
// ---------------------------------------------------------------------------
template<int HW, int LOGW, int NITER, int CMASK>
__global__ __launch_bounds__(256) void dw_kernel(
    const float* __restrict__ x, const float* __restrict__ w,
    float* __restrict__ out)
{
    const int bc = blockIdx.x;
    const int c  = bc & CMASK;
    const float* in = x + (size_t)bc * (HW * HW);
    float* o = out + (size_t)bc * (HW * HW);
    float wt[9];
#pragma unroll
    for (int i = 0; i < 9; ++i) wt[i] = w[c * 9 + i];
#pragma unroll
    for (int it = 0; it < NITER; ++it) {
        const int p   = threadIdx.x + it * 256;
        const int h   = p >> LOGW;
        const int col = p & (HW - 1);
        float s = 0.f;
#pragma unroll
        for (int dy = -1; dy <= 1; ++dy) {
            const int hh = h + dy;
            if (hh < 0 || hh >= HW) continue;
#pragma unroll
            for (int dx = -1; dx <= 1; ++dx) {
                const int ww = col + dx;
                if (ww < 0 || ww >= HW) continue;
                s = fmaf(in[hh * HW + ww], wt[(dy + 1) * 3 + (dx + 1)], s);
            }
        }
        o[p] = s;
    }
}

// ---------------------------------------------------------------------------
// pw1: out[b,o,hw] = sum_c in[b,c,hw] * w[o,c]   (C=128 -> O=256, 64x64 px)
// fused BN + ReLU + 2x2 maxpool -> t2 [32][256][32][32]
// Block: 256 thr. Tile: 64 out-ch x 128 px (2 rows of 64).
// thread: og=t>>4 (4 ch), tc=t&15 (cols 4tc..4tc+3, rows 0..1)
// ---------------------------------------------------------------------------
__global__ __launch_bounds__(256) void pw1_kernel(
    const float* __restrict__ t1, const float* __restrict__ w,
    const float* __restrict__ bg, const float* __restrict__ bb,
    const float* __restrict__ bm, const float* __restrict__ bv,
    float* __restrict__ t2)
{
    const int o0 = blockIdx.x * 64;
    const int hp = blockIdx.y;           // 0..31 (row pair)
    const int b  = blockIdx.z;
    const int t  = threadIdx.x;
    const int tc = t & 15;
    const int og = t >> 4;

    __shared__ float As[16][64];          // [k][o_local]
    __shared__ float Bs[16][128];         // [k][r*64+col]

    float acc[4][2][4];
#pragma unroll
    for (int i = 0; i < 4; ++i)
#pragma unroll
        for (int r = 0; r < 2; ++r)
#pragma unroll
            for (int j = 0; j < 4; ++j) acc[i][r][j] = 0.f;

    const int a_ol = t >> 2;              // 0..63
    const int a_k4 = (t & 3) * 4;         // 0,4,8,12
    const int b_rr = t >> 3;              // 0..31
    const int b_k  = b_rr >> 1;
    const int b_r  = b_rr & 1;
    const int b_col = (t & 7) * 8;
    const float* inb  = t1 + (size_t)(b * 128) * 4096 + (2 * hp) * 64;
    const float* arow = w + (size_t)(o0 + a_ol) * 128 + a_k4;

    for (int k0 = 0; k0 < 128; k0 += 16) {
        const float4 av = *(const float4*)(arow + k0);
        const float* src = inb + (size_t)(k0 + b_k) * 4096 + b_r * 64 + b_col;
        const float4 v0 = *(const float4*)src;
        const float4 v1 = *(const float4*)(src + 4);
        __syncthreads();
        As[a_k4 + 0][a_ol] = av.x;
        As[a_k4 + 1][a_ol] = av.y;
        As[a_k4 + 2][a_ol] = av.z;
        As[a_k4 + 3][a_ol] = av.w;
        *(float4*)&Bs[b_k][b_r * 64 + b_col]     = v0;
        *(float4*)&Bs[b_k][b_r * 64 + b_col + 4] = v1;
        __syncthreads();
#pragma unroll
        for (int kk = 0; kk < 16; ++kk) {
            const float4 a  = *(const float4*)&As[kk][4 * og];
            const float4 p0 = *(const float4*)&Bs[kk][4 * tc];
            const float4 p1 = *(const float4*)&Bs[kk][64 + 4 * tc];
            const float aa[4] = {a.x, a.y, a.z, a.w};
            const float q0[4] = {p0.x, p0.y, p0.z, p0.w};
            const float q1[4] = {p1.x, p1.y, p1.z, p1.w};
#pragma unroll
            for (int i = 0; i < 4; ++i) {
#pragma unroll
                for (int j = 0; j < 4; ++j) {
                    acc[i][0][j] = fmaf(aa[i], q0[j], acc[i][0][j]);
                    acc[i][1][j] = fmaf(aa[i], q1[j], acc[i][1][j]);
                }
            }
        }
    }

#pragma unroll
    for (int i = 0; i < 4; ++i) {
        const int o = o0 + 4 * og + i;
        const float s  = bg[o] * rsqrtf(bv[o] + BN_EPS);
        const float tt = bb[o] - bm[o] * s;
        float v[2][4];
#pragma unroll
        for (int r = 0; r < 2; ++r)
#pragma unroll
            for (int j = 0; j < 4; ++j)
                v[r][j] = fmaxf(fmaf(acc[i][r][j], s, tt), 0.f);
        const float out0 = fmaxf(fmaxf(v[0][0], v[0][1]), fmaxf(v[1][0], v[1][1]));
        const float out1 = fmaxf(fmaxf(v[0][2], v[0][3]), fmaxf(v[1][2], v[1][3]));
        *(float2*)&t2[(((size_t)(b * 256 + o)) * 32 + hp) * 32 + 2 * tc] =
            make_float2(out0, out1);
    }
}

// ---------------------------------------------------------------------------
// pw2: C=256 -> O=256 on 32x32 px, fused BN+ReLU+maxpool -> x [32][256][16][16]
// Block: 256 thr. Tile: 128 out-ch x 64 px (2 rows of 32).
// thread: og=t>>3 (4 ch), tc=t&7 (cols 4tc..4tc+3, rows 0..1)
// ---------------------------------------------------------------------------
__global__ __launch_bounds__(256) void pw2_kernel(
    const float* __restrict__ t3, const float* __restrict__ w,
    const float* __restrict__ bg, const float* __restrict__ bb,
    const float* __restrict__ bm, const float* __restrict__ bv,
    float* __restrict__ xout)
{
    const int o0 = blockIdx.x * 128;
    const int hp = blockIdx.y;            // 0..15
    const int b  = blockIdx.z;
    const int t  = threadIdx.x;
    const int tc = t & 7;
    const int og = t >> 3;                // 0..31

    __shared__ float As[16][128];
    __shared__ float Bs[16][64];

    float acc[4][2][4];
#pragma unroll
    for (int i = 0; i < 4; ++i)
#pragma unroll
        for (int r = 0; r < 2; ++r)
#pragma unroll
            for (int j = 0; j < 4; ++j) acc[i][r][j] = 0.f;

    const int a_ol = t >> 1;              // 0..127
    const int a_k8 = (t & 1) * 8;         // 0 or 8
    const int b_c  = t >> 4;              // 0..15
    const int b_pg = t & 15;
    const int b_r  = b_pg >> 3;
    const int b_col = (b_pg & 7) * 4;
    const float* inb  = t3 + (size_t)(b * 256) * 1024 + (2 * hp) * 32;
    const float* arow = w + (size_t)(o0 + a_ol) * 256 + a_k8;

    for (int k0 = 0; k0 < 256; k0 += 16) {
        const float4 av0 = *(const float4*)(arow + k0);
        const float4 av1 = *(const float4*)(arow + k0 + 4);
        const float* src = inb + (size_t)(k0 + b_c) * 1024 + b_r * 32 + b_col;
        const float4 v0 = *(const float4*)src;
        __syncthreads();
        As[a_k8 + 0][a_ol] = av0.x;
        As[a_k8 + 1][a_ol] = av0.y;
        As[a_k8 + 2][a_ol] = av0.z;
        As[a_k8 + 3][a_ol] = av0.w;
        As[a_k8 + 4][a_ol] = av1.x;
        As[a_k8 + 5][a_ol] = av1.y;
        As[a_k8 + 6][a_ol] = av1.z;
        As[a_k8 + 7][a_ol] = av1.w;
        *(float4*)&Bs[b_c][b_r * 32 + b_col] = v0;
        __syncthreads();
#pragma unroll
        for (int kk = 0; kk < 16; ++kk) {
            const float4 a  = *(const float4*)&As[kk][4 * og];
            const float4 p0 = *(const float4*)&Bs[kk][4 * tc];
            const float4 p1 = *(const float4*)&Bs[kk][32 + 4 * tc];
            const float aa[4] = {a.x, a.y, a.z, a.w};
            const float q0[4] = {p0.x, p0.y, p0.z, p0.w};
            const float q1[4] = {p1.x, p1.y, p1.z, p1.w};
#pragma unroll
            for (int i = 0; i < 4; ++i) {
#pragma unroll
                for (int j = 0; j < 4; ++j) {
                    acc[i][0][j] = fmaf(aa[i], q0[j], acc[i][0][j]);
                    acc[i][1][j] = fmaf(aa[i], q1[j], acc[i][1][j]);
                }
            }
        }
    }

#pragma unroll
    for (int i = 0; i < 4; ++i) {
        const int o = o0 + 4 * og + i;
        const float s  = bg[o] * rsqrtf(bv[o] + BN_EPS);
        const float tt = bb[o] - bm[o] * s;
        float v[2][4];
#pragma unroll
        for (int r = 0; r < 2; ++r)
#pragma unroll
            for (int j = 0; j < 4; ++j)
                v[r][j] = fmaxf(fmaf(acc[i][r][j], s, tt), 0.f);
        const float out0 = fmaxf(fmaxf(v[0][0], v[0][1]), fmaxf(v[1][0], v[1][1]));
        const float out1 = fmaxf(fmaxf(v[0][2], v[0][3]), fmaxf(v[1][2], v[1][3]));
        *(float2*)&xout[(((size_t)(b * 256 + o)) * 16 + hp) * 16 + 2 * tc] =
            make_float2(out0, out1);
    }
}

// ---------------------------------------------------------------------------
// cat: spikes[b,m,p] = sum_c x[b,c,p] * cw[m,c]   (m = k*8+o in 0..255,
// p in 0..255). Also catsum[b,m] = sum_p spikes[b,m,p].
// Block: 256 thr, tile 32 m x 256 px. og=t>>5 (4 m), tc=t&31 (8 px).
// ---------------------------------------------------------------------------
__global__ __launch_bounds__(256) void cat_kernel(
    const float* __restrict__ x, const float* __restrict__ cw,
    float* __restrict__ spikes, float* __restrict__ catsum)
{
    const int m0 = blockIdx.x * 32;
    const int b  = blockIdx.y;
    const int t  = threadIdx.x;
    const int tc = t & 31;
    const int og = t >> 5;                // 0..7

    __shared__ float As[16][32];
    __shared__ float Bs[16][256];

    float acc[4][8];
#pragma unroll
    for (int i = 0; i < 4; ++i)
#pragma unroll
        for (int j = 0; j < 8; ++j) acc[i][j] = 0.f;

    const int a_ml = t >> 3;              // 0..31
    const int a_k2 = (t & 7) * 2;         // 0..14
    const int b_c  = t >> 4;              // 0..15
    const int b_p  = (t & 15) * 16;
    const float* xb = x + (size_t)b * 65536;

    for (int k0 = 0; k0 < 256; k0 += 16) {
        const float2 av = *(const float2*)&cw[(size_t)(m0 + a_ml) * 256 + k0 + a_k2];
        const float* src = xb + (size_t)(k0 + b_c) * 256 + b_p;
        const float4 v0 = ((const float4*)src)[0];
        const float4 v1 = ((const float4*)src)[1];
        const float4 v2 = ((const float4*)src)[2];
        const float4 v3 = ((const float4*)src)[3];
        __syncthreads();
        As[a_k2 + 0][a_ml] = av.x;
        As[a_k2 + 1][a_ml] = av.y;
        ((float4*)&Bs[b_c][b_p])[0] = v0;
        ((float4*)&Bs[b_c][b_p])[1] = v1;
        ((float4*)&Bs[b_c][b_p])[2] = v2;
        ((float4*)&Bs[b_c][b_p])[3] = v3;
        __syncthreads();
#pragma unroll
        for (int kk = 0; kk < 16; ++kk) {
            const float4 a  = *(const float4*)&As[kk][4 * og];
            const float4 p0 = *(const float4*)&Bs[kk][8 * tc];
            const float4 p1 = *(const float4*)&Bs[kk][8 * tc + 4];
            const float aa[4] = {a.x, a.y, a.z, a.w};
            const float qq[8] = {p0.x, p0.y, p0.z, p0.w, p1.x, p1.y, p1.z, p1.w};
#pragma unroll
            for (int i = 0; i < 4; ++i)
#pragma unroll
                for (int j = 0; j < 8; ++j)
                    acc[i][j] = fmaf(aa[i], qq[j], acc[i][j]);
        }
    }

#pragma unroll
    for (int i = 0; i < 4; ++i) {
        const size_t base = ((size_t)(b * 256 + m0 + 4 * og + i)) * 256 + 8 * tc;
        *(float4*)&spikes[base]     = make_float4(acc[i][0], acc[i][1], acc[i][2], acc[i][3]);
        *(float4*)&spikes[base + 4] = make_float4(acc[i][4], acc[i][5], acc[i][6], acc[i][7]);
        float s = 0.f;
#pragma unroll
        for (int j = 0; j < 8; ++j) s += acc[i][j];
        s += __shfl_xor(s, 1, 64);
        s += __shfl_xor(s, 2, 64);
        s += __shfl_xor(s, 4, 64);
        s += __shfl_xor(s, 8, 64);
        s += __shfl_xor(s, 16, 64);
        if (tc == 0) catsum[b * 256 + m0 + 4 * og + i] = s;
    }
}

// ---------------------------------------------------------------------------
// final: pooled mean over pixels, embedding GEMV, category activations.
// One block per b, 256 threads.
// ---------------------------------------------------------------------------
__global__ __launch_bounds__(256) void final_kernel(
    const float* __restrict__ x, const float* __restrict__ catsum,
    const float* __restrict__ embw, const float* __restrict__ embb,
    float* __restrict__ cat_act, float* __restrict__ emb)
{
    const int b = blockIdx.x;
    const int t = threadIdx.x;
    __shared__ __align__(16) float pooled[256];

    // pooled[c] = mean over 256 pixels
    {
        const float4* src = (const float4*)(x + (size_t)b * 65536 + (size_t)t * 256);
        float s = 0.f;
#pragma unroll 8
        for (int i = 0; i < 64; ++i) {
            const float4 v = src[i];
            s += v.x + v.y + v.z + v.w;
        }
        pooled[t] = s * (1.0f / 256.0f);
    }
    __syncthreads();

    if (t < 128) {
        const float4* wr = (const float4*)(embw + (size_t)t * 256);
        float d = 0.f;
#pragma unroll 8
        for (int i = 0; i < 64; ++i) {
            const float4 wv = wr[i];
            const float4 pv = *(const float4*)&pooled[4 * i];
            d = fmaf(wv.x, pv.x, d);
            d = fmaf(wv.y, pv.y, d);
            d = fmaf(wv.z, pv.z, d);
            d = fmaf(wv.w, pv.w, d);
        }
        emb[b * 128 + t] = d + embb[t];
    } else if (t < 160) {
        const int k = t - 128;
        float s = 0.f;
#pragma unroll
        for (int o = 0; o < 8; ++o) s += catsum[b * 256 + k * 8 + o];
        cat_act[b * 32 + k] = s * (1.0f / 2048.0f);
    }
}

// ---------------------------------------------------------------------------
extern "C" void kernel_launch(void* const* d_in, const int* in_sizes, int n_in,
                              void* d_out, int out_size, void* d_ws, size_t ws_size,
                              hipStream_t stream) {
    const float* v4   = (const float*)d_in[0];
    const float* w1dw = (const float*)d_in[1];
    const float* w1pw = (const float*)d_in[2];
    const float* bn1g = (const float*)d_in[3];
    const float* bn1b = (const float*)d_in[4];
    const float* bn1m = (const float*)d_in[5];
    const float* bn1v = (const float*)d_in[6];
    const float* w2dw = (const float*)d_in[7];
    const float* w2pw = (const float*)d_in[8];
    const float* bn2g = (const float*)d_in[9];
    const float* bn2b = (const float*)d_in[10];
    const float* bn2m = (const float*)d_in[11];
    const float* bn2v = (const float*)d_in[12];
    const float* catw = (const float*)d_in[13];
    const float* embw = (const float*)d_in[14];
    const float* embb = (const float*)d_in[15];

    float* out        = (float*)d_out;
    float* cat_spikes = out;                    // [32][256][256] = 2097152
    float* cat_act    = out + 2097152;          // [32][32]       = 1024
    float* emb        = out + 2098176;          // [32][128]      = 4096
    float* xout       = out + 2102272;          // [32][256][256] = 2097152

    char* ws = (char*)d_ws;
    float* t1     = (float*)ws;                            // 64 MB (reused as t3)
    float* t2     = (float*)(ws + 67108864);               // 33.5 MB
    float* catsum = (float*)(ws + 67108864 + 33554432);    // 32 KB

    // Block 1
    dw_kernel<64, 6, 16, 127><<<4096, 256, 0, stream>>>(v4, w1dw, t1);
    pw1_kernel<<<dim3(4, 32, 32), 256, 0, stream>>>(t1, w1pw, bn1g, bn1b, bn1m, bn1v, t2);
    // Block 2 (t3 reuses t1's buffer)
    dw_kernel<32, 5, 4, 255><<<8192, 256, 0, stream>>>(t2, w2dw, t1);
    pw2_kernel<<<dim3(2, 16, 32), 256, 0, stream>>>(t1, w2pw, bn2g, bn2b, bn2m, bn2v, xout);
    // Category contraction + pooled sums
    cat_kernel<<<dim3(8, 32), 256, 0, stream>>>(xout, catw, cat_spikes, catsum);
    // Final reductions
    final_kernel<<<32, 256, 0, stream>>>(xout, catsum, embw, embb, cat_act, emb);
}

// Round 4
// 210.378 us; speedup vs baseline: 1.5561x; 1.5561x over previous
//
#include <hip/hip_runtime.h>

#define BN_EPS 1e-5f

typedef float f32x4 __attribute__((ext_vector_type(4)));
typedef short short8 __attribute__((ext_vector_type(8)));

__device__ __forceinline__ unsigned short f2bf(float f) {
    unsigned u = __builtin_bit_cast(unsigned, f);
    unsigned r = (u + 0x7FFFu + ((u >> 16) & 1u)) >> 16;   // round-nearest-even
    return (unsigned short)r;
}

// ---------------------------------------------------------------------------
// Depthwise 3x3, SAME, vectorized: each thread computes a 16-px row segment.
// 12 float4 + 6 scalar loads, 48 fma, 4 float4 stores per thread.
// HW=plane side, PPB=planes/block, CMASK=C-1, LOG_TPP=log2(256/PPB),
// LOG_SEGS=log2(HW/16).
// ---------------------------------------------------------------------------
template<int HW, int PPB, int CMASK, int LOG_TPP, int LOG_SEGS>
__global__ __launch_bounds__(256) void dw_vec(
    const float* __restrict__ in, const float* __restrict__ wts,
    float* __restrict__ out)
{
    const int t     = threadIdx.x;
    const int TPP   = 256 / PPB;
    const int local = t & (TPP - 1);
    const int plane = blockIdx.x * PPB + (t >> LOG_TPP);
    const int SEGS  = HW / 16;
    const int row   = local >> LOG_SEGS;
    const int seg   = local & (SEGS - 1);
    const int c     = plane & CMASK;
    const int w0    = seg * 16;

    const float* ip = in  + (size_t)plane * (HW * HW);
    float*       op = out + (size_t)plane * (HW * HW);

    float wt[9];
#pragma unroll
    for (int i = 0; i < 9; ++i) wt[i] = wts[c * 9 + i];

    float acc[16];
#pragma unroll
    for (int i = 0; i < 16; ++i) acc[i] = 0.f;

#pragma unroll
    for (int dr = -1; dr <= 1; ++dr) {
        const int r = row + dr;
        if (r < 0 || r >= HW) continue;
        const float* rp = ip + r * HW + w0;
        float arr[18];
        arr[0]  = (w0 > 0) ? rp[-1] : 0.f;
        const float4 v0 = *(const float4*)(rp);
        const float4 v1 = *(const float4*)(rp + 4);
        const float4 v2 = *(const float4*)(rp + 8);
        const float4 v3 = *(const float4*)(rp + 12);
        arr[1]  = v0.x; arr[2]  = v0.y; arr[3]  = v0.z; arr[4]  = v0.w;
        arr[5]  = v1.x; arr[6]  = v1.y; arr[7]  = v1.z; arr[8]  = v1.w;
        arr[9]  = v2.x; arr[10] = v2.y; arr[11] = v2.z; arr[12] = v2.w;
        arr[13] = v3.x; arr[14] = v3.y; arr[15] = v3.z; arr[16] = v3.w;
        arr[17] = (w0 + 16 < HW) ? rp[16] : 0.f;
        const float wa = wt[(dr + 1) * 3 + 0];
        const float wb = wt[(dr + 1) * 3 + 1];
        const float wc = wt[(dr + 1) * 3 + 2];
#pragma unroll
        for (int i = 0; i < 16; ++i)
            acc[i] = fmaf(arr[i], wa, fmaf(arr[i + 1], wb, fmaf(arr[i + 2], wc, acc[i])));
    }

#pragma unroll
    for (int q = 0; q < 4; ++q)
        *(float4*)(op + row * HW + w0 + 4 * q) =
            make_float4(acc[4 * q], acc[4 * q + 1], acc[4 * q + 2], acc[4 * q + 3]);
}

// ---------------------------------------------------------------------------
// pw1 via bf16 MFMA 16x16x32: C[o,p] = sum_c W[o,c]*X[c,p], K=128 resident.
// Block: 64 o x 128 p (2 image rows), 4 waves (2o x 2p), fused BN+ReLU+pool.
// LDS: A [64][128]bf16 swz (16K) + B [128][128]bf16 swz (32K), reused as
// Dbuf [64][130]f32; sArr/tArr at tail. Swizzle: byte ^= ((row&7)<<4).
// ---------------------------------------------------------------------------
__global__ __launch_bounds__(256) void pw1_mfma(
    const float* __restrict__ t1, const float* __restrict__ w,
    const float* __restrict__ bg, const float* __restrict__ bb,
    const float* __restrict__ bm, const float* __restrict__ bv,
    float* __restrict__ t2)
{
    __shared__ __align__(16) char smem[49664];
    float* sArr = (float*)(smem + 49152);    // [64]
    float* tArr = (float*)(smem + 49408);    // [64]
    float* Df   = (float*)smem;              // [64][130] f32 (reuses A+B)

    const int o0 = blockIdx.x * 64;
    const int p0 = blockIdx.y * 128;         // two image rows
    const int b  = blockIdx.z;
    const int t  = threadIdx.x;

    // ---- stage A: W[o0..o0+63][0..127] fp32 -> bf16, swizzled ----
#pragma unroll
    for (int i = 0; i < 8; ++i) {
        const int li = i * 256 + t;          // [0,2048)
        const int ol = li >> 5;
        const int f4 = li & 31;
        const float4 wv = *(const float4*)(w + (size_t)(o0 + ol) * 128 + 4 * f4);
        ushort4 h;
        h.x = f2bf(wv.x); h.y = f2bf(wv.y); h.z = f2bf(wv.z); h.w = f2bf(wv.w);
        const int byteo = (ol * 256 + f4 * 8) ^ ((ol & 7) << 4);
        *(ushort4*)(smem + byteo) = h;
    }

    // ---- stage B: X[c][p0..p0+127] fp32 -> transposed bf16 [p][c], swizzled ----
    const float* xb = t1 + ((size_t)b * 128) * 4096 + p0;
#pragma unroll
    for (int i = 0; i < 4; ++i) {
        const int li = i * 256 + t;          // [0,1024)
        const int c4 = li >> 5;              // c = 4*c4 .. +3
        const int f4 = li & 31;              // p = 4*f4 .. +3
        float4 v0 = *(const float4*)(xb + (size_t)(4 * c4 + 0) * 4096 + 4 * f4);
        float4 v1 = *(const float4*)(xb + (size_t)(4 * c4 + 1) * 4096 + 4 * f4);
        float4 v2 = *(const float4*)(xb + (size_t)(4 * c4 + 2) * 4096 + 4 * f4);
        float4 v3 = *(const float4*)(xb + (size_t)(4 * c4 + 3) * 4096 + 4 * f4);
        ushort4 h0, h1, h2, h3;              // per-p, 4 c's each
        h0.x = f2bf(v0.x); h0.y = f2bf(v1.x); h0.z = f2bf(v2.x); h0.w = f2bf(v3.x);
        h1.x = f2bf(v0.y); h1.y = f2bf(v1.y); h1.z = f2bf(v2.y); h1.w = f2bf(v3.y);
        h2.x = f2bf(v0.z); h2.y = f2bf(v1.z); h2.z = f2bf(v2.z); h2.w = f2bf(v3.z);
        h3.x = f2bf(v0.w); h3.y = f2bf(v1.w); h3.z = f2bf(v2.w); h3.w = f2bf(v3.w);
        const int p_0 = 4 * f4;
        *(ushort4*)(smem + 16384 + (((p_0 + 0) * 256 + 8 * c4) ^ (((p_0 + 0) & 7) << 4))) = h0;
        *(ushort4*)(smem + 16384 + (((p_0 + 1) * 256 + 8 * c4) ^ (((p_0 + 1) & 7) << 4))) = h1;
        *(ushort4*)(smem + 16384 + (((p_0 + 2) * 256 + 8 * c4) ^ (((p_0 + 2) & 7) << 4))) = h2;
        *(ushort4*)(smem + 16384 + (((p_0 + 3) * 256 + 8 * c4) ^ (((p_0 + 3) & 7) << 4))) = h3;
    }

    if (t < 64) {
        const int o = o0 + t;
        const float s = bg[o] * rsqrtf(bv[o] + BN_EPS);
        sArr[t] = s;
        tArr[t] = bb[o] - bm[o] * s;
    }
    __syncthreads();

    // ---- K-loop: 32 MFMA per wave, all operands LDS-resident ----
    const int lane = t & 63, wid = t >> 6;
    const int lr = lane & 15, lg = lane >> 4;
    const int wo = (wid >> 1) * 32;
    const int wp = (wid & 1) * 64;

    f32x4 acc[2][4];
#pragma unroll
    for (int m = 0; m < 2; ++m)
#pragma unroll
        for (int n = 0; n < 4; ++n) acc[m][n] = (f32x4){0.f, 0.f, 0.f, 0.f};

#pragma unroll
    for (int ks = 0; ks < 4; ++ks) {
        short8 af[2];
#pragma unroll
        for (int m = 0; m < 2; ++m) {
            const int rowm = wo + m * 16 + lr;
            af[m] = *(const short8*)(smem + ((rowm * 256 + ks * 64 + lg * 16) ^ ((rowm & 7) << 4)));
        }
#pragma unroll
        for (int n = 0; n < 4; ++n) {
            const int prow = wp + n * 16 + lr;
            const short8 bfv = *(const short8*)(smem + 16384 +
                ((prow * 256 + ks * 64 + lg * 16) ^ ((prow & 7) << 4)));
            acc[0][n] = __builtin_amdgcn_mfma_f32_16x16x32_bf16(af[0], bfv, acc[0][n], 0, 0, 0);
            acc[1][n] = __builtin_amdgcn_mfma_f32_16x16x32_bf16(af[1], bfv, acc[1][n], 0, 0, 0);
        }
    }
    __syncthreads();   // all LDS frag reads done before Dbuf overwrite

    // ---- BN + ReLU -> Dbuf ----
    float sv[2][4], tv[2][4];
#pragma unroll
    for (int m = 0; m < 2; ++m)
#pragma unroll
        for (int j = 0; j < 4; ++j) {
            const int ol = wo + m * 16 + 4 * lg + j;
            sv[m][j] = sArr[ol];
            tv[m][j] = tArr[ol];
        }
#pragma unroll
    for (int m = 0; m < 2; ++m)
#pragma unroll
        for (int n = 0; n < 4; ++n)
#pragma unroll
            for (int j = 0; j < 4; ++j) {
                const int ol = wo + m * 16 + 4 * lg + j;
                const int pl = wp + n * 16 + lr;
                const float val = fmaf(acc[m][n][j], sv[m][j], tv[m][j]);
                Df[ol * 130 + pl] = fmaxf(val, 0.f);
            }
    __syncthreads();

    // ---- 2x2 maxpool -> t2[b][o][hp][wp] ----
#pragma unroll
    for (int i = 0; i < 8; ++i) {
        const int oi  = i * 256 + t;         // [0,2048)
        const int o   = oi >> 5;
        const int wpx = oi & 31;
        const float a0 = Df[o * 130 + 2 * wpx];
        const float a1 = Df[o * 130 + 2 * wpx + 1];
        const float b0 = Df[o * 130 + 64 + 2 * wpx];
        const float b1 = Df[o * 130 + 64 + 2 * wpx + 1];
        t2[(((size_t)(b * 256 + o0 + o)) * 32 + blockIdx.y) * 32 + wpx] =
            fmaxf(fmaxf(a0, a1), fmaxf(b0, b1));
    }
}

// ---------------------------------------------------------------------------
// pw2: C=256 -> O=256 on 32x32 px, fused BN+ReLU+maxpool -> x [32][256][16][16]
// (unchanged fp32 version)
// ---------------------------------------------------------------------------
__global__ __launch_bounds__(256) void pw2_kernel(
    const float* __restrict__ t3, const float* __restrict__ w,
    const float* __restrict__ bg, const float* __restrict__ bb,
    const float* __restrict__ bm, const float* __restrict__ bv,
    float* __restrict__ xout)
{
    const int o0 = blockIdx.x * 128;
    const int hp = blockIdx.y;            // 0..15
    const int b  = blockIdx.z;
    const int t  = threadIdx.x;
    const int tc = t & 7;
    const int og = t >> 3;                // 0..31

    __shared__ float As[16][128];
    __shared__ float Bs[16][64];

    float acc[4][2][4];
#pragma unroll
    for (int i = 0; i < 4; ++i)
#pragma unroll
        for (int r = 0; r < 2; ++r)
#pragma unroll
            for (int j = 0; j < 4; ++j) acc[i][r][j] = 0.f;

    const int a_ol = t >> 1;              // 0..127
    const int a_k8 = (t & 1) * 8;         // 0 or 8
    const int b_c  = t >> 4;              // 0..15
    const int b_pg = t & 15;
    const int b_r  = b_pg >> 3;
    const int b_col = (b_pg & 7) * 4;
    const float* inb  = t3 + (size_t)(b * 256) * 1024 + (2 * hp) * 32;
    const float* arow = w + (size_t)(o0 + a_ol) * 256 + a_k8;

    for (int k0 = 0; k0 < 256; k0 += 16) {
        const float4 av0 = *(const float4*)(arow + k0);
        const float4 av1 = *(const float4*)(arow + k0 + 4);
        const float* src = inb + (size_t)(k0 + b_c) * 1024 + b_r * 32 + b_col;
        const float4 v0 = *(const float4*)src;
        __syncthreads();
        As[a_k8 + 0][a_ol] = av0.x;
        As[a_k8 + 1][a_ol] = av0.y;
        As[a_k8 + 2][a_ol] = av0.z;
        As[a_k8 + 3][a_ol] = av0.w;
        As[a_k8 + 4][a_ol] = av1.x;
        As[a_k8 + 5][a_ol] = av1.y;
        As[a_k8 + 6][a_ol] = av1.z;
        As[a_k8 + 7][a_ol] = av1.w;
        *(float4*)&Bs[b_c][b_r * 32 + b_col] = v0;
        __syncthreads();
#pragma unroll
        for (int kk = 0; kk < 16; ++kk) {
            const float4 a  = *(const float4*)&As[kk][4 * og];
            const float4 p0 = *(const float4*)&Bs[kk][4 * tc];
            const float4 p1 = *(const float4*)&Bs[kk][32 + 4 * tc];
            const float aa[4] = {a.x, a.y, a.z, a.w};
            const float q0[4] = {p0.x, p0.y, p0.z, p0.w};
            const float q1[4] = {p1.x, p1.y, p1.z, p1.w};
#pragma unroll
            for (int i = 0; i < 4; ++i) {
#pragma unroll
                for (int j = 0; j < 4; ++j) {
                    acc[i][0][j] = fmaf(aa[i], q0[j], acc[i][0][j]);
                    acc[i][1][j] = fmaf(aa[i], q1[j], acc[i][1][j]);
                }
            }
        }
    }

#pragma unroll
    for (int i = 0; i < 4; ++i) {
        const int o = o0 + 4 * og + i;
        const float s  = bg[o] * rsqrtf(bv[o] + BN_EPS);
        const float tt = bb[o] - bm[o] * s;
        float v[2][4];
#pragma unroll
        for (int r = 0; r < 2; ++r)
#pragma unroll
            for (int j = 0; j < 4; ++j)
                v[r][j] = fmaxf(fmaf(acc[i][r][j], s, tt), 0.f);
        const float out0 = fmaxf(fmaxf(v[0][0], v[0][1]), fmaxf(v[1][0], v[1][1]));
        const float out1 = fmaxf(fmaxf(v[0][2], v[0][3]), fmaxf(v[1][2], v[1][3]));
        *(float2*)&xout[(((size_t)(b * 256 + o)) * 16 + hp) * 16 + 2 * tc] =
            make_float2(out0, out1);
    }
}

// ---------------------------------------------------------------------------
// cat: spikes[b,m,p] = sum_c x[b,c,p] * cw[m,c]; catsum[b,m] = sum_p spikes.
// (unchanged fp32 version)
// ---------------------------------------------------------------------------
__global__ __launch_bounds__(256) void cat_kernel(
    const float* __restrict__ x, const float* __restrict__ cw,
    float* __restrict__ spikes, float* __restrict__ catsum)
{
    const int m0 = blockIdx.x * 32;
    const int b  = blockIdx.y;
    const int t  = threadIdx.x;
    const int tc = t & 31;
    const int og = t >> 5;                // 0..7

    __shared__ float As[16][32];
    __shared__ float Bs[16][256];

    float acc[4][8];
#pragma unroll
    for (int i = 0; i < 4; ++i)
#pragma unroll
        for (int j = 0; j < 8; ++j) acc[i][j] = 0.f;

    const int a_ml = t >> 3;              // 0..31
    const int a_k2 = (t & 7) * 2;         // 0..14
    const int b_c  = t >> 4;              // 0..15
    const int b_p  = (t & 15) * 16;
    const float* xb = x + (size_t)b * 65536;

    for (int k0 = 0; k0 < 256; k0 += 16) {
        const float2 av = *(const float2*)&cw[(size_t)(m0 + a_ml) * 256 + k0 + a_k2];
        const float* src = xb + (size_t)(k0 + b_c) * 256 + b_p;
        const float4 v0 = ((const float4*)src)[0];
        const float4 v1 = ((const float4*)src)[1];
        const float4 v2 = ((const float4*)src)[2];
        const float4 v3 = ((const float4*)src)[3];
        __syncthreads();
        As[a_k2 + 0][a_ml] = av.x;
        As[a_k2 + 1][a_ml] = av.y;
        ((float4*)&Bs[b_c][b_p])[0] = v0;
        ((float4*)&Bs[b_c][b_p])[1] = v1;
        ((float4*)&Bs[b_c][b_p])[2] = v2;
        ((float4*)&Bs[b_c][b_p])[3] = v3;
        __syncthreads();
#pragma unroll
        for (int kk = 0; kk < 16; ++kk) {
            const float4 a  = *(const float4*)&As[kk][4 * og];
            const float4 p0 = *(const float4*)&Bs[kk][8 * tc];
            const float4 p1 = *(const float4*)&Bs[kk][8 * tc + 4];
            const float aa[4] = {a.x, a.y, a.z, a.w};
            const float qq[8] = {p0.x, p0.y, p0.z, p0.w, p1.x, p1.y, p1.z, p1.w};
#pragma unroll
            for (int i = 0; i < 4; ++i)
#pragma unroll
                for (int j = 0; j < 8; ++j)
                    acc[i][j] = fmaf(aa[i], qq[j], acc[i][j]);
        }
    }

#pragma unroll
    for (int i = 0; i < 4; ++i) {
        const size_t base = ((size_t)(b * 256 + m0 + 4 * og + i)) * 256 + 8 * tc;
        *(float4*)&spikes[base]     = make_float4(acc[i][0], acc[i][1], acc[i][2], acc[i][3]);
        *(float4*)&spikes[base + 4] = make_float4(acc[i][4], acc[i][5], acc[i][6], acc[i][7]);
        float s = 0.f;
#pragma unroll
        for (int j = 0; j < 8; ++j) s += acc[i][j];
        s += __shfl_xor(s, 1, 64);
        s += __shfl_xor(s, 2, 64);
        s += __shfl_xor(s, 4, 64);
        s += __shfl_xor(s, 8, 64);
        s += __shfl_xor(s, 16, 64);
        if (tc == 0) catsum[b * 256 + m0 + 4 * og + i] = s;
    }
}

// ---------------------------------------------------------------------------
// final: pooled mean over pixels, embedding GEMV, category activations.
// ---------------------------------------------------------------------------
__global__ __launch_bounds__(256) void final_kernel(
    const float* __restrict__ x, const float* __restrict__ catsum,
    const float* __restrict__ embw, const float* __restrict__ embb,
    float* __restrict__ cat_act, float* __restrict__ emb)
{
    const int b = blockIdx.x;
    const int t = threadIdx.x;
    __shared__ __align__(16) float pooled[256];

    {
        const float4* src = (const float4*)(x + (size_t)b * 65536 + (size_t)t * 256);
        float s = 0.f;
#pragma unroll 8
        for (int i = 0; i < 64; ++i) {
            const float4 v = src[i];
            s += v.x + v.y + v.z + v.w;
        }
        pooled[t] = s * (1.0f / 256.0f);
    }
    __syncthreads();

    if (t < 128) {
        const float4* wr = (const float4*)(embw + (size_t)t * 256);
        float d = 0.f;
#pragma unroll 8
        for (int i = 0; i < 64; ++i) {
            const float4 wv = wr[i];
            const float4 pv = *(const float4*)&pooled[4 * i];
            d = fmaf(wv.x, pv.x, d);
            d = fmaf(wv.y, pv.y, d);
            d = fmaf(wv.z, pv.z, d);
            d = fmaf(wv.w, pv.w, d);
        }
        emb[b * 128 + t] = d + embb[t];
    } else if (t < 160) {
        const int k = t - 128;
        float s = 0.f;
#pragma unroll
        for (int o = 0; o < 8; ++o) s += catsum[b * 256 + k * 8 + o];
        cat_act[b * 32 + k] = s * (1.0f / 2048.0f);
    }
}

// ---------------------------------------------------------------------------
extern "C" void kernel_launch(void* const* d_in, const int* in_sizes, int n_in,
                              void* d_out, int out_size, void* d_ws, size_t ws_size,
                              hipStream_t stream) {
    const float* v4   = (const float*)d_in[0];
    const float* w1dw = (const float*)d_in[1];
    const float* w1pw = (const float*)d_in[2];
    const float* bn1g = (const float*)d_in[3];
    const float* bn1b = (const float*)d_in[4];
    const float* bn1m = (const float*)d_in[5];
    const float* bn1v = (const float*)d_in[6];
    const float* w2dw = (const float*)d_in[7];
    const float* w2pw = (const float*)d_in[8];
    const float* bn2g = (const float*)d_in[9];
    const float* bn2b = (const float*)d_in[10];
    const float* bn2m = (const float*)d_in[11];
    const float* bn2v = (const float*)d_in[12];
    const float* catw = (const float*)d_in[13];
    const float* embw = (const float*)d_in[14];
    const float* embb = (const float*)d_in[15];

    float* out        = (float*)d_out;
    float* cat_spikes = out;                    // [32][256][256]
    float* cat_act    = out + 2097152;          // [32][32]
    float* emb        = out + 2098176;          // [32][128]
    float* xout       = out + 2102272;          // [32][256][256]

    char* ws = (char*)d_ws;
    float* t1     = (float*)ws;                            // 64 MB (reused as t3)
    float* t2     = (float*)(ws + 67108864);               // 33.5 MB
    float* catsum = (float*)(ws + 67108864 + 33554432);    // 32 KB

    // Block 1
    dw_vec<64, 1, 127, 8, 2><<<4096, 256, 0, stream>>>(v4, w1dw, t1);
    pw1_mfma<<<dim3(4, 32, 32), 256, 0, stream>>>(t1, w1pw, bn1g, bn1b, bn1m, bn1v, t2);
    // Block 2 (t3 reuses t1's buffer)
    dw_vec<32, 4, 255, 6, 1><<<2048, 256, 0, stream>>>(t2, w2dw, t1);
    pw2_kernel<<<dim3(2, 16, 32), 256, 0, stream>>>(t1, w2pw, bn2g, bn2b, bn2m, bn2v, xout);
    // Category contraction + pooled sums
    cat_kernel<<<dim3(8, 32), 256, 0, stream>>>(xout, catw, cat_spikes, catsum);
    // Final reductions
    final_kernel<<<32, 256, 0, stream>>>(xout, catsum, embw, embb, cat_act, emb);
}

// Round 5
// 164.050 us; speedup vs baseline: 1.9956x; 1.2824x over previous
//
#include <hip/hip_runtime.h>

#define BN_EPS 1e-5f

typedef float f32x4 __attribute__((ext_vector_type(4)));
typedef short short8 __attribute__((ext_vector_type(8)));

__device__ __forceinline__ unsigned short f2bf(float f) {
    unsigned u = __builtin_bit_cast(unsigned, f);
    unsigned r = (u + 0x7FFFu + ((u >> 16) & 1u)) >> 16;   // round-nearest-even
    return (unsigned short)r;
}

// ---------------------------------------------------------------------------
// Depthwise 3x3, SAME, vectorized: each thread computes a 16-px row segment.
// ---------------------------------------------------------------------------
template<int HW, int PPB, int CMASK, int LOG_TPP, int LOG_SEGS>
__global__ __launch_bounds__(256) void dw_vec(
    const float* __restrict__ in, const float* __restrict__ wts,
    float* __restrict__ out)
{
    const int t     = threadIdx.x;
    const int TPP   = 256 / PPB;
    const int local = t & (TPP - 1);
    const int plane = blockIdx.x * PPB + (t >> LOG_TPP);
    const int SEGS  = HW / 16;
    const int row   = local >> LOG_SEGS;
    const int seg   = local & (SEGS - 1);
    const int c     = plane & CMASK;
    const int w0    = seg * 16;

    const float* ip = in  + (size_t)plane * (HW * HW);
    float*       op = out + (size_t)plane * (HW * HW);

    float wt[9];
#pragma unroll
    for (int i = 0; i < 9; ++i) wt[i] = wts[c * 9 + i];

    float acc[16];
#pragma unroll
    for (int i = 0; i < 16; ++i) acc[i] = 0.f;

#pragma unroll
    for (int dr = -1; dr <= 1; ++dr) {
        const int r = row + dr;
        if (r < 0 || r >= HW) continue;
        const float* rp = ip + r * HW + w0;
        float arr[18];
        arr[0]  = (w0 > 0) ? rp[-1] : 0.f;
        const float4 v0 = *(const float4*)(rp);
        const float4 v1 = *(const float4*)(rp + 4);
        const float4 v2 = *(const float4*)(rp + 8);
        const float4 v3 = *(const float4*)(rp + 12);
        arr[1]  = v0.x; arr[2]  = v0.y; arr[3]  = v0.z; arr[4]  = v0.w;
        arr[5]  = v1.x; arr[6]  = v1.y; arr[7]  = v1.z; arr[8]  = v1.w;
        arr[9]  = v2.x; arr[10] = v2.y; arr[11] = v2.z; arr[12] = v2.w;
        arr[13] = v3.x; arr[14] = v3.y; arr[15] = v3.z; arr[16] = v3.w;
        arr[17] = (w0 + 16 < HW) ? rp[16] : 0.f;
        const float wa = wt[(dr + 1) * 3 + 0];
        const float wb = wt[(dr + 1) * 3 + 1];
        const float wc = wt[(dr + 1) * 3 + 2];
#pragma unroll
        for (int i = 0; i < 16; ++i)
            acc[i] = fmaf(arr[i], wa, fmaf(arr[i + 1], wb, fmaf(arr[i + 2], wc, acc[i])));
    }

#pragma unroll
    for (int q = 0; q < 4; ++q)
        *(float4*)(op + row * HW + w0 + 4 * q) =
            make_float4(acc[4 * q], acc[4 * q + 1], acc[4 * q + 2], acc[4 * q + 3]);
}

// ---------------------------------------------------------------------------
// pw1 via bf16 MFMA 16x16x32: 64o x 128px, K=128 resident. Fused BN+ReLU+pool.
// ---------------------------------------------------------------------------
__global__ __launch_bounds__(256) void pw1_mfma(
    const float* __restrict__ t1, const float* __restrict__ w,
    const float* __restrict__ bg, const float* __restrict__ bb,
    const float* __restrict__ bm, const float* __restrict__ bv,
    float* __restrict__ t2)
{
    __shared__ __align__(16) char smem[49664];
    float* sArr = (float*)(smem + 49152);    // [64]
    float* tArr = (float*)(smem + 49408);    // [64]
    float* Df   = (float*)smem;              // [64][130] f32 (reuses A+B)

    const int o0 = blockIdx.x * 64;
    const int p0 = blockIdx.y * 128;         // two image rows
    const int b  = blockIdx.z;
    const int t  = threadIdx.x;

#pragma unroll
    for (int i = 0; i < 8; ++i) {
        const int li = i * 256 + t;
        const int ol = li >> 5;
        const int f4 = li & 31;
        const float4 wv = *(const float4*)(w + (size_t)(o0 + ol) * 128 + 4 * f4);
        ushort4 h;
        h.x = f2bf(wv.x); h.y = f2bf(wv.y); h.z = f2bf(wv.z); h.w = f2bf(wv.w);
        const int byteo = (ol * 256 + f4 * 8) ^ ((ol & 7) << 4);
        *(ushort4*)(smem + byteo) = h;
    }

    const float* xb = t1 + ((size_t)b * 128) * 4096 + p0;
#pragma unroll
    for (int i = 0; i < 4; ++i) {
        const int li = i * 256 + t;
        const int c4 = li >> 5;
        const int f4 = li & 31;
        float4 v0 = *(const float4*)(xb + (size_t)(4 * c4 + 0) * 4096 + 4 * f4);
        float4 v1 = *(const float4*)(xb + (size_t)(4 * c4 + 1) * 4096 + 4 * f4);
        float4 v2 = *(const float4*)(xb + (size_t)(4 * c4 + 2) * 4096 + 4 * f4);
        float4 v3 = *(const float4*)(xb + (size_t)(4 * c4 + 3) * 4096 + 4 * f4);
        ushort4 h0, h1, h2, h3;
        h0.x = f2bf(v0.x); h0.y = f2bf(v1.x); h0.z = f2bf(v2.x); h0.w = f2bf(v3.x);
        h1.x = f2bf(v0.y); h1.y = f2bf(v1.y); h1.z = f2bf(v2.y); h1.w = f2bf(v3.y);
        h2.x = f2bf(v0.z); h2.y = f2bf(v1.z); h2.z = f2bf(v2.z); h2.w = f2bf(v3.z);
        h3.x = f2bf(v0.w); h3.y = f2bf(v1.w); h3.z = f2bf(v2.w); h3.w = f2bf(v3.w);
        const int p_0 = 4 * f4;
        *(ushort4*)(smem + 16384 + (((p_0 + 0) * 256 + 8 * c4) ^ (((p_0 + 0) & 7) << 4))) = h0;
        *(ushort4*)(smem + 16384 + (((p_0 + 1) * 256 + 8 * c4) ^ (((p_0 + 1) & 7) << 4))) = h1;
        *(ushort4*)(smem + 16384 + (((p_0 + 2) * 256 + 8 * c4) ^ (((p_0 + 2) & 7) << 4))) = h2;
        *(ushort4*)(smem + 16384 + (((p_0 + 3) * 256 + 8 * c4) ^ (((p_0 + 3) & 7) << 4))) = h3;
    }

    if (t < 64) {
        const int o = o0 + t;
        const float s = bg[o] * rsqrtf(bv[o] + BN_EPS);
        sArr[t] = s;
        tArr[t] = bb[o] - bm[o] * s;
    }
    __syncthreads();

    const int lane = t & 63, wid = t >> 6;
    const int lr = lane & 15, lg = lane >> 4;
    const int wo = (wid >> 1) * 32;
    const int wp = (wid & 1) * 64;

    f32x4 acc[2][4];
#pragma unroll
    for (int m = 0; m < 2; ++m)
#pragma unroll
        for (int n = 0; n < 4; ++n) acc[m][n] = (f32x4){0.f, 0.f, 0.f, 0.f};

#pragma unroll
    for (int ks = 0; ks < 4; ++ks) {
        short8 af[2];
#pragma unroll
        for (int m = 0; m < 2; ++m) {
            const int rowm = wo + m * 16 + lr;
            af[m] = *(const short8*)(smem + ((rowm * 256 + ks * 64 + lg * 16) ^ ((rowm & 7) << 4)));
        }
#pragma unroll
        for (int n = 0; n < 4; ++n) {
            const int prow = wp + n * 16 + lr;
            const short8 bfv = *(const short8*)(smem + 16384 +
                ((prow * 256 + ks * 64 + lg * 16) ^ ((prow & 7) << 4)));
            acc[0][n] = __builtin_amdgcn_mfma_f32_16x16x32_bf16(af[0], bfv, acc[0][n], 0, 0, 0);
            acc[1][n] = __builtin_amdgcn_mfma_f32_16x16x32_bf16(af[1], bfv, acc[1][n], 0, 0, 0);
        }
    }
    __syncthreads();

    float sv[2][4], tv[2][4];
#pragma unroll
    for (int m = 0; m < 2; ++m)
#pragma unroll
        for (int j = 0; j < 4; ++j) {
            const int ol = wo + m * 16 + 4 * lg + j;
            sv[m][j] = sArr[ol];
            tv[m][j] = tArr[ol];
        }
#pragma unroll
    for (int m = 0; m < 2; ++m)
#pragma unroll
        for (int n = 0; n < 4; ++n)
#pragma unroll
            for (int j = 0; j < 4; ++j) {
                const int ol = wo + m * 16 + 4 * lg + j;
                const int pl = wp + n * 16 + lr;
                const float val = fmaf(acc[m][n][j], sv[m][j], tv[m][j]);
                Df[ol * 130 + pl] = fmaxf(val, 0.f);
            }
    __syncthreads();

#pragma unroll
    for (int i = 0; i < 8; ++i) {
        const int oi  = i * 256 + t;
        const int o   = oi >> 5;
        const int wpx = oi & 31;
        const float a0 = Df[o * 130 + 2 * wpx];
        const float a1 = Df[o * 130 + 2 * wpx + 1];
        const float b0 = Df[o * 130 + 64 + 2 * wpx];
        const float b1 = Df[o * 130 + 64 + 2 * wpx + 1];
        t2[(((size_t)(b * 256 + o0 + o)) * 32 + blockIdx.y) * 32 + wpx] =
            fmaxf(fmaxf(a0, a1), fmaxf(b0, b1));
    }
}

// ---------------------------------------------------------------------------
// pw2 via bf16 MFMA: C=256 -> O=256 on 32x32 px. Tile 64o x 128px (4 image
// rows), K=256 as 2 x BK=128 stages. LDS: A [64][128]bf16 swz 16K @0,
// B [128px][128c]bf16 swz 32K @16384; Dbuf [64][130]f32 reuse; sArr/tArr tail.
// Fused BN+ReLU+2x2pool -> xout [32][256][16][16].
// ---------------------------------------------------------------------------
__global__ __launch_bounds__(256) void pw2_mfma(
    const float* __restrict__ t3, const float* __restrict__ w,
    const float* __restrict__ bg, const float* __restrict__ bb,
    const float* __restrict__ bm, const float* __restrict__ bv,
    float* __restrict__ xout)
{
    __shared__ __align__(16) char smem[49664];
    float* sArr = (float*)(smem + 49152);
    float* tArr = (float*)(smem + 49408);
    float* Df   = (float*)smem;              // [64][130]

    const int o0 = blockIdx.x * 64;          // 4 tiles
    const int p0 = blockIdx.y * 128;         // 8 tiles (4 image rows each)
    const int b  = blockIdx.z;
    const int t  = threadIdx.x;

    const int lane = t & 63, wid = t >> 6;
    const int lr = lane & 15, lg = lane >> 4;
    const int wo = (wid >> 1) * 32;
    const int wp = (wid & 1) * 64;

    f32x4 acc[2][4];
#pragma unroll
    for (int m = 0; m < 2; ++m)
#pragma unroll
        for (int n = 0; n < 4; ++n) acc[m][n] = (f32x4){0.f, 0.f, 0.f, 0.f};

#pragma unroll
    for (int ko = 0; ko < 2; ++ko) {
        if (ko) __syncthreads();             // prior MFMA reads done

        // stage A: W[o0..+64)[ko*128..+128) -> bf16 swz
#pragma unroll
        for (int i = 0; i < 8; ++i) {
            const int li = i * 256 + t;
            const int ol = li >> 5;
            const int f4 = li & 31;
            const float4 wv = *(const float4*)(w + (size_t)(o0 + ol) * 256 + ko * 128 + 4 * f4);
            ushort4 h;
            h.x = f2bf(wv.x); h.y = f2bf(wv.y); h.z = f2bf(wv.z); h.w = f2bf(wv.w);
            *(ushort4*)(smem + ((ol * 256 + f4 * 8) ^ ((ol & 7) << 4))) = h;
        }

        // stage B: X[c][p0..+128) transposed -> [p][c] bf16 swz
        const float* xb = t3 + ((size_t)b * 256 + ko * 128) * 1024 + p0;
#pragma unroll
        for (int i = 0; i < 4; ++i) {
            const int li = i * 256 + t;
            const int c4 = li >> 5;
            const int f4 = li & 31;
            float4 v0 = *(const float4*)(xb + (size_t)(4 * c4 + 0) * 1024 + 4 * f4);
            float4 v1 = *(const float4*)(xb + (size_t)(4 * c4 + 1) * 1024 + 4 * f4);
            float4 v2 = *(const float4*)(xb + (size_t)(4 * c4 + 2) * 1024 + 4 * f4);
            float4 v3 = *(const float4*)(xb + (size_t)(4 * c4 + 3) * 1024 + 4 * f4);
            ushort4 h0, h1, h2, h3;
            h0.x = f2bf(v0.x); h0.y = f2bf(v1.x); h0.z = f2bf(v2.x); h0.w = f2bf(v3.x);
            h1.x = f2bf(v0.y); h1.y = f2bf(v1.y); h1.z = f2bf(v2.y); h1.w = f2bf(v3.y);
            h2.x = f2bf(v0.z); h2.y = f2bf(v1.z); h2.z = f2bf(v2.z); h2.w = f2bf(v3.z);
            h3.x = f2bf(v0.w); h3.y = f2bf(v1.w); h3.z = f2bf(v2.w); h3.w = f2bf(v3.w);
            const int p_0 = 4 * f4;
            *(ushort4*)(smem + 16384 + (((p_0 + 0) * 256 + 8 * c4) ^ (((p_0 + 0) & 7) << 4))) = h0;
            *(ushort4*)(smem + 16384 + (((p_0 + 1) * 256 + 8 * c4) ^ (((p_0 + 1) & 7) << 4))) = h1;
            *(ushort4*)(smem + 16384 + (((p_0 + 2) * 256 + 8 * c4) ^ (((p_0 + 2) & 7) << 4))) = h2;
            *(ushort4*)(smem + 16384 + (((p_0 + 3) * 256 + 8 * c4) ^ (((p_0 + 3) & 7) << 4))) = h3;
        }

        if (ko == 0 && t < 64) {
            const int o = o0 + t;
            const float s = bg[o] * rsqrtf(bv[o] + BN_EPS);
            sArr[t] = s;
            tArr[t] = bb[o] - bm[o] * s;
        }
        __syncthreads();

#pragma unroll
        for (int ks = 0; ks < 4; ++ks) {
            short8 af[2];
#pragma unroll
            for (int m = 0; m < 2; ++m) {
                const int rowm = wo + m * 16 + lr;
                af[m] = *(const short8*)(smem + ((rowm * 256 + ks * 64 + lg * 16) ^ ((rowm & 7) << 4)));
            }
#pragma unroll
            for (int n = 0; n < 4; ++n) {
                const int prow = wp + n * 16 + lr;
                const short8 bfv = *(const short8*)(smem + 16384 +
                    ((prow * 256 + ks * 64 + lg * 16) ^ ((prow & 7) << 4)));
                acc[0][n] = __builtin_amdgcn_mfma_f32_16x16x32_bf16(af[0], bfv, acc[0][n], 0, 0, 0);
                acc[1][n] = __builtin_amdgcn_mfma_f32_16x16x32_bf16(af[1], bfv, acc[1][n], 0, 0, 0);
            }
        }
    }
    __syncthreads();

    // BN + ReLU -> Dbuf
    float sv[2][4], tv[2][4];
#pragma unroll
    for (int m = 0; m < 2; ++m)
#pragma unroll
        for (int j = 0; j < 4; ++j) {
            const int ol = wo + m * 16 + 4 * lg + j;
            sv[m][j] = sArr[ol];
            tv[m][j] = tArr[ol];
        }
#pragma unroll
    for (int m = 0; m < 2; ++m)
#pragma unroll
        for (int n = 0; n < 4; ++n)
#pragma unroll
            for (int j = 0; j < 4; ++j) {
                const int ol = wo + m * 16 + 4 * lg + j;
                const int pl = wp + n * 16 + lr;
                const float val = fmaf(acc[m][n][j], sv[m][j], tv[m][j]);
                Df[ol * 130 + pl] = fmaxf(val, 0.f);
            }
    __syncthreads();

    // 2x2 maxpool: 4 local rows of 32 -> 2 pooled rows of 16
#pragma unroll
    for (int i = 0; i < 8; ++i) {
        const int oi = i * 256 + t;          // [0,2048)
        const int o  = oi >> 5;              // 0..63
        const int q  = oi & 31;
        const int prl = q >> 4;              // pooled row 0..1
        const int pc  = q & 15;              // pooled col
        const float a0 = Df[o * 130 + prl * 64 + 2 * pc];
        const float a1 = Df[o * 130 + prl * 64 + 2 * pc + 1];
        const float b0 = Df[o * 130 + prl * 64 + 32 + 2 * pc];
        const float b1 = Df[o * 130 + prl * 64 + 32 + 2 * pc + 1];
        xout[(((size_t)(b * 256 + o0 + o)) * 16 + 2 * blockIdx.y + prl) * 16 + pc] =
            fmaxf(fmaxf(a0, a1), fmaxf(b0, b1));
    }
}

// ---------------------------------------------------------------------------
// cat via bf16 MFMA: spikes[b,m,p] = sum_c x[b,c,p]*cw[m,c], m tile 32,
// full P=256 per block, K=256 as 4 x BK=64. LDS: A [32][64]bf16 swz 4K @0,
// B [256][64]bf16 swz 32K @4096. catsum computed block-locally (no atomics).
// ---------------------------------------------------------------------------
__global__ __launch_bounds__(256) void cat_mfma(
    const float* __restrict__ x, const float* __restrict__ cw,
    float* __restrict__ spikes, float* __restrict__ catsum)
{
    __shared__ __align__(16) char smem[36864];
    __shared__ float cs[4][32];

    const int m0 = blockIdx.x * 32;          // 8 tiles
    const int b  = blockIdx.y;
    const int t  = threadIdx.x;

    const int lane = t & 63, wid = t >> 6;
    const int lr = lane & 15, lg = lane >> 4;
    const int wp = wid * 64;                 // wave's 64-px range

    f32x4 acc[2][4];
#pragma unroll
    for (int m = 0; m < 2; ++m)
#pragma unroll
        for (int n = 0; n < 4; ++n) acc[m][n] = (f32x4){0.f, 0.f, 0.f, 0.f};

    const float* xb = x + (size_t)b * 65536;

#pragma unroll
    for (int ks = 0; ks < 4; ++ks) {
        if (ks) __syncthreads();

        // stage A: cw[m0..+32)[ks*64..+64) -> bf16 swz (rows of 128B)
#pragma unroll
        for (int i = 0; i < 2; ++i) {
            const int li = i * 256 + t;      // [0,512)
            const int ml = li >> 4;          // 0..31
            const int f4 = li & 15;          // 0..15
            const float4 wv = *(const float4*)(cw + (size_t)(m0 + ml) * 256 + ks * 64 + 4 * f4);
            ushort4 h;
            h.x = f2bf(wv.x); h.y = f2bf(wv.y); h.z = f2bf(wv.z); h.w = f2bf(wv.w);
            *(ushort4*)(smem + ((ml * 128 + f4 * 8) ^ ((ml & 7) << 4))) = h;
        }

        // stage B: x[c][p] transposed -> [p][c] bf16 swz, c in ks*64+[0,64)
#pragma unroll
        for (int i = 0; i < 4; ++i) {
            const int li = i * 256 + t;      // [0,1024)
            const int c4 = li >> 6;          // 0..15
            const int f4 = li & 63;          // 0..63
            float4 v0 = *(const float4*)(xb + (size_t)(ks * 64 + 4 * c4 + 0) * 256 + 4 * f4);
            float4 v1 = *(const float4*)(xb + (size_t)(ks * 64 + 4 * c4 + 1) * 256 + 4 * f4);
            float4 v2 = *(const float4*)(xb + (size_t)(ks * 64 + 4 * c4 + 2) * 256 + 4 * f4);
            float4 v3 = *(const float4*)(xb + (size_t)(ks * 64 + 4 * c4 + 3) * 256 + 4 * f4);
            ushort4 h0, h1, h2, h3;
            h0.x = f2bf(v0.x); h0.y = f2bf(v1.x); h0.z = f2bf(v2.x); h0.w = f2bf(v3.x);
            h1.x = f2bf(v0.y); h1.y = f2bf(v1.y); h1.z = f2bf(v2.y); h1.w = f2bf(v3.y);
            h2.x = f2bf(v0.z); h2.y = f2bf(v1.z); h2.z = f2bf(v2.z); h2.w = f2bf(v3.z);
            h3.x = f2bf(v0.w); h3.y = f2bf(v1.w); h3.z = f2bf(v2.w); h3.w = f2bf(v3.w);
            const int p_0 = 4 * f4;
            *(ushort4*)(smem + 4096 + (((p_0 + 0) * 128 + 8 * c4) ^ (((p_0 + 0) & 7) << 4))) = h0;
            *(ushort4*)(smem + 4096 + (((p_0 + 1) * 128 + 8 * c4) ^ (((p_0 + 1) & 7) << 4))) = h1;
            *(ushort4*)(smem + 4096 + (((p_0 + 2) * 128 + 8 * c4) ^ (((p_0 + 2) & 7) << 4))) = h2;
            *(ushort4*)(smem + 4096 + (((p_0 + 3) * 128 + 8 * c4) ^ (((p_0 + 3) & 7) << 4))) = h3;
        }
        __syncthreads();

#pragma unroll
        for (int kk = 0; kk < 2; ++kk) {
            short8 af[2];
#pragma unroll
            for (int m = 0; m < 2; ++m) {
                const int rowm = m * 16 + lr;
                af[m] = *(const short8*)(smem + ((rowm * 128 + kk * 64 + lg * 16) ^ ((rowm & 7) << 4)));
            }
#pragma unroll
            for (int n = 0; n < 4; ++n) {
                const int prow = wp + n * 16 + lr;
                const short8 bfv = *(const short8*)(smem + 4096 +
                    ((prow * 128 + kk * 64 + lg * 16) ^ ((prow & 7) << 4)));
                acc[0][n] = __builtin_amdgcn_mfma_f32_16x16x32_bf16(af[0], bfv, acc[0][n], 0, 0, 0);
                acc[1][n] = __builtin_amdgcn_mfma_f32_16x16x32_bf16(af[1], bfv, acc[1][n], 0, 0, 0);
            }
        }
    }

    // write spikes + per-m px sums
#pragma unroll
    for (int mi = 0; mi < 2; ++mi) {
#pragma unroll
        for (int j = 0; j < 4; ++j) {
            const int m = m0 + mi * 16 + 4 * lg + j;
#pragma unroll
            for (int n = 0; n < 4; ++n)
                spikes[((size_t)(b * 256 + m)) * 256 + wp + n * 16 + lr] = acc[mi][n][j];
            float s = acc[mi][0][j] + acc[mi][1][j] + acc[mi][2][j] + acc[mi][3][j];
            s += __shfl_xor(s, 1, 64);
            s += __shfl_xor(s, 2, 64);
            s += __shfl_xor(s, 4, 64);
            s += __shfl_xor(s, 8, 64);
            if (lr == 0) cs[wid][mi * 16 + 4 * lg + j] = s;
        }
    }
    __syncthreads();
    if (t < 32)
        catsum[b * 256 + m0 + t] = cs[0][t] + cs[1][t] + cs[2][t] + cs[3][t];
}

// ---------------------------------------------------------------------------
// final: pooled mean over pixels, embedding GEMV, category activations.
// ---------------------------------------------------------------------------
__global__ __launch_bounds__(256) void final_kernel(
    const float* __restrict__ x, const float* __restrict__ catsum,
    const float* __restrict__ embw, const float* __restrict__ embb,
    float* __restrict__ cat_act, float* __restrict__ emb)
{
    const int b = blockIdx.x;
    const int t = threadIdx.x;
    __shared__ __align__(16) float pooled[256];

    {
        const float4* src = (const float4*)(x + (size_t)b * 65536 + (size_t)t * 256);
        float s = 0.f;
#pragma unroll 8
        for (int i = 0; i < 64; ++i) {
            const float4 v = src[i];
            s += v.x + v.y + v.z + v.w;
        }
        pooled[t] = s * (1.0f / 256.0f);
    }
    __syncthreads();

    if (t < 128) {
        const float4* wr = (const float4*)(embw + (size_t)t * 256);
        float d = 0.f;
#pragma unroll 8
        for (int i = 0; i < 64; ++i) {
            const float4 wv = wr[i];
            const float4 pv = *(const float4*)&pooled[4 * i];
            d = fmaf(wv.x, pv.x, d);
            d = fmaf(wv.y, pv.y, d);
            d = fmaf(wv.z, pv.z, d);
            d = fmaf(wv.w, pv.w, d);
        }
        emb[b * 128 + t] = d + embb[t];
    } else if (t < 160) {
        const int k = t - 128;
        float s = 0.f;
#pragma unroll
        for (int o = 0; o < 8; ++o) s += catsum[b * 256 + k * 8 + o];
        cat_act[b * 32 + k] = s * (1.0f / 2048.0f);
    }
}

// ---------------------------------------------------------------------------
extern "C" void kernel_launch(void* const* d_in, const int* in_sizes, int n_in,
                              void* d_out, int out_size, void* d_ws, size_t ws_size,
                              hipStream_t stream) {
    const float* v4   = (const float*)d_in[0];
    const float* w1dw = (const float*)d_in[1];
    const float* w1pw = (const float*)d_in[2];
    const float* bn1g = (const float*)d_in[3];
    const float* bn1b = (const float*)d_in[4];
    const float* bn1m = (const float*)d_in[5];
    const float* bn1v = (const float*)d_in[6];
    const float* w2dw = (const float*)d_in[7];
    const float* w2pw = (const float*)d_in[8];
    const float* bn2g = (const float*)d_in[9];
    const float* bn2b = (const float*)d_in[10];
    const float* bn2m = (const float*)d_in[11];
    const float* bn2v = (const float*)d_in[12];
    const float* catw = (const float*)d_in[13];
    const float* embw = (const float*)d_in[14];
    const float* embb = (const float*)d_in[15];

    float* out        = (float*)d_out;
    float* cat_spikes = out;                    // [32][256][256]
    float* cat_act    = out + 2097152;          // [32][32]
    float* emb        = out + 2098176;          // [32][128]
    float* xout       = out + 2102272;          // [32][256][256]

    char* ws = (char*)d_ws;
    float* t1     = (float*)ws;                            // 64 MB (reused as t3)
    float* t2     = (float*)(ws + 67108864);               // 33.5 MB
    float* catsum = (float*)(ws + 67108864 + 33554432);    // 32 KB

    // Block 1
    dw_vec<64, 1, 127, 8, 2><<<4096, 256, 0, stream>>>(v4, w1dw, t1);
    pw1_mfma<<<dim3(4, 32, 32), 256, 0, stream>>>(t1, w1pw, bn1g, bn1b, bn1m, bn1v, t2);
    // Block 2 (t3 reuses t1's buffer)
    dw_vec<32, 4, 255, 6, 1><<<2048, 256, 0, stream>>>(t2, w2dw, t1);
    pw2_mfma<<<dim3(4, 8, 32), 256, 0, stream>>>(t1, w2pw, bn2g, bn2b, bn2m, bn2v, xout);
    // Category contraction + pooled sums
    cat_mfma<<<dim3(8, 32), 256, 0, stream>>>(xout, catw, cat_spikes, catsum);
    // Final reductions
    final_kernel<<<32, 256, 0, stream>>>(xout, catsum, embw, embb, cat_act, emb);
}

// Round 6
// 149.840 us; speedup vs baseline: 2.1849x; 1.0948x over previous
//
#include <hip/hip_runtime.h>

#define BN_EPS 1e-5f

typedef float f32x4 __attribute__((ext_vector_type(4)));
typedef short short8 __attribute__((ext_vector_type(8)));

__device__ __forceinline__ unsigned short f2bf(float f) {
    unsigned u = __builtin_bit_cast(unsigned, f);
    unsigned r = (u + 0x7FFFu + ((u >> 16) & 1u)) >> 16;   // round-nearest-even
    return (unsigned short)r;
}

// ---------------------------------------------------------------------------
// Depthwise 3x3, SAME, lane-contiguous: each thread owns 4 consecutive px.
// HW/4 lanes cover one row; horizontal neighbors via shfl, vertical via
// adjacent-row loads (L1-hit). All global ops fully coalesced.
// NPL = planes/block, IPP = 1024-px iters/plane.
// ---------------------------------------------------------------------------
template<int HW, int LOGW, int NPL, int IPP, int CMASK>
__global__ __launch_bounds__(256) void dw_shfl(
    const float* __restrict__ in, const float* __restrict__ wts,
    float* __restrict__ out)
{
    const int t   = threadIdx.x;
    const int LPR = HW / 4;                 // lanes per row
    const int wq  = t & (LPR - 1);
    const int w0  = wq * 4;
    const int rin = t >> (LOGW - 2);        // row within 1024-px chunk

    for (int pl = 0; pl < NPL; ++pl) {
        const int plane = blockIdx.x * NPL + pl;
        const int c     = plane & CMASK;
        float wt[9];
#pragma unroll
        for (int i = 0; i < 9; ++i) wt[i] = wts[c * 9 + i];
        const float* ip = in  + (size_t)plane * (HW * HW);
        float*       op = out + (size_t)plane * (HW * HW);

#pragma unroll
        for (int it = 0; it < IPP; ++it) {
            const int h = it * (1024 / HW) + rin;
            const float* rp = ip + h * HW + w0;
            const float4 zero4 = make_float4(0.f, 0.f, 0.f, 0.f);
            const float4 vc = *(const float4*)rp;
            const float4 vt = (h > 0)      ? *(const float4*)(rp - HW) : zero4;
            const float4 vb = (h < HW - 1) ? *(const float4*)(rp + HW) : zero4;

            float lc = __shfl_up(vc.w, 1),  rc = __shfl_down(vc.x, 1);
            float lt = __shfl_up(vt.w, 1),  rt = __shfl_down(vt.x, 1);
            float lb = __shfl_up(vb.w, 1),  rb = __shfl_down(vb.x, 1);
            if (wq == 0)       { lc = 0.f; lt = 0.f; lb = 0.f; }
            if (wq == LPR - 1) { rc = 0.f; rt = 0.f; rb = 0.f; }

            float o0 = 0.f, o1 = 0.f, o2 = 0.f, o3 = 0.f;
            // top row
            o0 = fmaf(lt,   wt[0], fmaf(vt.x, wt[1], fmaf(vt.y, wt[2], o0)));
            o1 = fmaf(vt.x, wt[0], fmaf(vt.y, wt[1], fmaf(vt.z, wt[2], o1)));
            o2 = fmaf(vt.y, wt[0], fmaf(vt.z, wt[1], fmaf(vt.w, wt[2], o2)));
            o3 = fmaf(vt.z, wt[0], fmaf(vt.w, wt[1], fmaf(rt,   wt[2], o3)));
            // center row
            o0 = fmaf(lc,   wt[3], fmaf(vc.x, wt[4], fmaf(vc.y, wt[5], o0)));
            o1 = fmaf(vc.x, wt[3], fmaf(vc.y, wt[4], fmaf(vc.z, wt[5], o1)));
            o2 = fmaf(vc.y, wt[3], fmaf(vc.z, wt[4], fmaf(vc.w, wt[5], o2)));
            o3 = fmaf(vc.z, wt[3], fmaf(vc.w, wt[4], fmaf(rc,   wt[5], o3)));
            // bottom row
            o0 = fmaf(lb,   wt[6], fmaf(vb.x, wt[7], fmaf(vb.y, wt[8], o0)));
            o1 = fmaf(vb.x, wt[6], fmaf(vb.y, wt[7], fmaf(vb.z, wt[8], o1)));
            o2 = fmaf(vb.y, wt[6], fmaf(vb.z, wt[7], fmaf(vb.w, wt[8], o2)));
            o3 = fmaf(vb.z, wt[6], fmaf(vb.w, wt[7], fmaf(rb,   wt[8], o3)));

            *(float4*)(op + h * HW + w0) = make_float4(o0, o1, o2, o3);
        }
    }
}

// ---------------------------------------------------------------------------
// pw1 via bf16 MFMA 16x16x32: 64o x 128px, K=128 resident. Fused BN+ReLU+pool.
// ---------------------------------------------------------------------------
__global__ __launch_bounds__(256) void pw1_mfma(
    const float* __restrict__ t1, const float* __restrict__ w,
    const float* __restrict__ bg, const float* __restrict__ bb,
    const float* __restrict__ bm, const float* __restrict__ bv,
    float* __restrict__ t2)
{
    __shared__ __align__(16) char smem[49664];
    float* sArr = (float*)(smem + 49152);    // [64]
    float* tArr = (float*)(smem + 49408);    // [64]
    float* Df   = (float*)smem;              // [64][130] f32 (reuses A+B)

    const int o0 = blockIdx.x * 64;
    const int p0 = blockIdx.y * 128;         // two image rows
    const int b  = blockIdx.z;
    const int t  = threadIdx.x;

#pragma unroll
    for (int i = 0; i < 8; ++i) {
        const int li = i * 256 + t;
        const int ol = li >> 5;
        const int f4 = li & 31;
        const float4 wv = *(const float4*)(w + (size_t)(o0 + ol) * 128 + 4 * f4);
        ushort4 h;
        h.x = f2bf(wv.x); h.y = f2bf(wv.y); h.z = f2bf(wv.z); h.w = f2bf(wv.w);
        const int byteo = (ol * 256 + f4 * 8) ^ ((ol & 7) << 4);
        *(ushort4*)(smem + byteo) = h;
    }

    const float* xb = t1 + ((size_t)b * 128) * 4096 + p0;
#pragma unroll
    for (int i = 0; i < 4; ++i) {
        const int li = i * 256 + t;
        const int c4 = li >> 5;
        const int f4 = li & 31;
        float4 v0 = *(const float4*)(xb + (size_t)(4 * c4 + 0) * 4096 + 4 * f4);
        float4 v1 = *(const float4*)(xb + (size_t)(4 * c4 + 1) * 4096 + 4 * f4);
        float4 v2 = *(const float4*)(xb + (size_t)(4 * c4 + 2) * 4096 + 4 * f4);
        float4 v3 = *(const float4*)(xb + (size_t)(4 * c4 + 3) * 4096 + 4 * f4);
        ushort4 h0, h1, h2, h3;
        h0.x = f2bf(v0.x); h0.y = f2bf(v1.x); h0.z = f2bf(v2.x); h0.w = f2bf(v3.x);
        h1.x = f2bf(v0.y); h1.y = f2bf(v1.y); h1.z = f2bf(v2.y); h1.w = f2bf(v3.y);
        h2.x = f2bf(v0.z); h2.y = f2bf(v1.z); h2.z = f2bf(v2.z); h2.w = f2bf(v3.z);
        h3.x = f2bf(v0.w); h3.y = f2bf(v1.w); h3.z = f2bf(v2.w); h3.w = f2bf(v3.w);
        const int p_0 = 4 * f4;
        *(ushort4*)(smem + 16384 + (((p_0 + 0) * 256 + 8 * c4) ^ (((p_0 + 0) & 7) << 4))) = h0;
        *(ushort4*)(smem + 16384 + (((p_0 + 1) * 256 + 8 * c4) ^ (((p_0 + 1) & 7) << 4))) = h1;
        *(ushort4*)(smem + 16384 + (((p_0 + 2) * 256 + 8 * c4) ^ (((p_0 + 2) & 7) << 4))) = h2;
        *(ushort4*)(smem + 16384 + (((p_0 + 3) * 256 + 8 * c4) ^ (((p_0 + 3) & 7) << 4))) = h3;
    }

    if (t < 64) {
        const int o = o0 + t;
        const float s = bg[o] * rsqrtf(bv[o] + BN_EPS);
        sArr[t] = s;
        tArr[t] = bb[o] - bm[o] * s;
    }
    __syncthreads();

    const int lane = t & 63, wid = t >> 6;
    const int lr = lane & 15, lg = lane >> 4;
    const int wo = (wid >> 1) * 32;
    const int wp = (wid & 1) * 64;

    f32x4 acc[2][4];
#pragma unroll
    for (int m = 0; m < 2; ++m)
#pragma unroll
        for (int n = 0; n < 4; ++n) acc[m][n] = (f32x4){0.f, 0.f, 0.f, 0.f};

#pragma unroll
    for (int ks = 0; ks < 4; ++ks) {
        short8 af[2];
#pragma unroll
        for (int m = 0; m < 2; ++m) {
            const int rowm = wo + m * 16 + lr;
            af[m] = *(const short8*)(smem + ((rowm * 256 + ks * 64 + lg * 16) ^ ((rowm & 7) << 4)));
        }
#pragma unroll
        for (int n = 0; n < 4; ++n) {
            const int prow = wp + n * 16 + lr;
            const short8 bfv = *(const short8*)(smem + 16384 +
                ((prow * 256 + ks * 64 + lg * 16) ^ ((prow & 7) << 4)));
            acc[0][n] = __builtin_amdgcn_mfma_f32_16x16x32_bf16(af[0], bfv, acc[0][n], 0, 0, 0);
            acc[1][n] = __builtin_amdgcn_mfma_f32_16x16x32_bf16(af[1], bfv, acc[1][n], 0, 0, 0);
        }
    }
    __syncthreads();

    float sv[2][4], tv[2][4];
#pragma unroll
    for (int m = 0; m < 2; ++m)
#pragma unroll
        for (int j = 0; j < 4; ++j) {
            const int ol = wo + m * 16 + 4 * lg + j;
            sv[m][j] = sArr[ol];
            tv[m][j] = tArr[ol];
        }
#pragma unroll
    for (int m = 0; m < 2; ++m)
#pragma unroll
        for (int n = 0; n < 4; ++n)
#pragma unroll
            for (int j = 0; j < 4; ++j) {
                const int ol = wo + m * 16 + 4 * lg + j;
                const int pl = wp + n * 16 + lr;
                const float val = fmaf(acc[m][n][j], sv[m][j], tv[m][j]);
                Df[ol * 130 + pl] = fmaxf(val, 0.f);
            }
    __syncthreads();

#pragma unroll
    for (int i = 0; i < 8; ++i) {
        const int oi  = i * 256 + t;
        const int o   = oi >> 5;
        const int wpx = oi & 31;
        const float a0 = Df[o * 130 + 2 * wpx];
        const float a1 = Df[o * 130 + 2 * wpx + 1];
        const float b0 = Df[o * 130 + 64 + 2 * wpx];
        const float b1 = Df[o * 130 + 64 + 2 * wpx + 1];
        t2[(((size_t)(b * 256 + o0 + o)) * 32 + blockIdx.y) * 32 + wpx] =
            fmaxf(fmaxf(a0, a1), fmaxf(b0, b1));
    }
}

// ---------------------------------------------------------------------------
// pw2 via bf16 MFMA: C=256 -> O=256 on 32x32 px. Tile 64o x 128px, K=256 as
// 2 x BK=128 stages. Fused BN+ReLU+2x2pool -> xout [32][256][16][16].
// ---------------------------------------------------------------------------
__global__ __launch_bounds__(256) void pw2_mfma(
    const float* __restrict__ t3, const float* __restrict__ w,
    const float* __restrict__ bg, const float* __restrict__ bb,
    const float* __restrict__ bm, const float* __restrict__ bv,
    float* __restrict__ xout)
{
    __shared__ __align__(16) char smem[49664];
    float* sArr = (float*)(smem + 49152);
    float* tArr = (float*)(smem + 49408);
    float* Df   = (float*)smem;              // [64][130]

    const int o0 = blockIdx.x * 64;
    const int p0 = blockIdx.y * 128;
    const int b  = blockIdx.z;
    const int t  = threadIdx.x;

    const int lane = t & 63, wid = t >> 6;
    const int lr = lane & 15, lg = lane >> 4;
    const int wo = (wid >> 1) * 32;
    const int wp = (wid & 1) * 64;

    f32x4 acc[2][4];
#pragma unroll
    for (int m = 0; m < 2; ++m)
#pragma unroll
        for (int n = 0; n < 4; ++n) acc[m][n] = (f32x4){0.f, 0.f, 0.f, 0.f};

#pragma unroll
    for (int ko = 0; ko < 2; ++ko) {
        if (ko) __syncthreads();

#pragma unroll
        for (int i = 0; i < 8; ++i) {
            const int li = i * 256 + t;
            const int ol = li >> 5;
            const int f4 = li & 31;
            const float4 wv = *(const float4*)(w + (size_t)(o0 + ol) * 256 + ko * 128 + 4 * f4);
            ushort4 h;
            h.x = f2bf(wv.x); h.y = f2bf(wv.y); h.z = f2bf(wv.z); h.w = f2bf(wv.w);
            *(ushort4*)(smem + ((ol * 256 + f4 * 8) ^ ((ol & 7) << 4))) = h;
        }

        const float* xb = t3 + ((size_t)b * 256 + ko * 128) * 1024 + p0;
#pragma unroll
        for (int i = 0; i < 4; ++i) {
            const int li = i * 256 + t;
            const int c4 = li >> 5;
            const int f4 = li & 31;
            float4 v0 = *(const float4*)(xb + (size_t)(4 * c4 + 0) * 1024 + 4 * f4);
            float4 v1 = *(const float4*)(xb + (size_t)(4 * c4 + 1) * 1024 + 4 * f4);
            float4 v2 = *(const float4*)(xb + (size_t)(4 * c4 + 2) * 1024 + 4 * f4);
            float4 v3 = *(const float4*)(xb + (size_t)(4 * c4 + 3) * 1024 + 4 * f4);
            ushort4 h0, h1, h2, h3;
            h0.x = f2bf(v0.x); h0.y = f2bf(v1.x); h0.z = f2bf(v2.x); h0.w = f2bf(v3.x);
            h1.x = f2bf(v0.y); h1.y = f2bf(v1.y); h1.z = f2bf(v2.y); h1.w = f2bf(v3.y);
            h2.x = f2bf(v0.z); h2.y = f2bf(v1.z); h2.z = f2bf(v2.z); h2.w = f2bf(v3.z);
            h3.x = f2bf(v0.w); h3.y = f2bf(v1.w); h3.z = f2bf(v2.w); h3.w = f2bf(v3.w);
            const int p_0 = 4 * f4;
            *(ushort4*)(smem + 16384 + (((p_0 + 0) * 256 + 8 * c4) ^ (((p_0 + 0) & 7) << 4))) = h0;
            *(ushort4*)(smem + 16384 + (((p_0 + 1) * 256 + 8 * c4) ^ (((p_0 + 1) & 7) << 4))) = h1;
            *(ushort4*)(smem + 16384 + (((p_0 + 2) * 256 + 8 * c4) ^ (((p_0 + 2) & 7) << 4))) = h2;
            *(ushort4*)(smem + 16384 + (((p_0 + 3) * 256 + 8 * c4) ^ (((p_0 + 3) & 7) << 4))) = h3;
        }

        if (ko == 0 && t < 64) {
            const int o = o0 + t;
            const float s = bg[o] * rsqrtf(bv[o] + BN_EPS);
            sArr[t] = s;
            tArr[t] = bb[o] - bm[o] * s;
        }
        __syncthreads();

#pragma unroll
        for (int ks = 0; ks < 4; ++ks) {
            short8 af[2];
#pragma unroll
            for (int m = 0; m < 2; ++m) {
                const int rowm = wo + m * 16 + lr;
                af[m] = *(const short8*)(smem + ((rowm * 256 + ks * 64 + lg * 16) ^ ((rowm & 7) << 4)));
            }
#pragma unroll
            for (int n = 0; n < 4; ++n) {
                const int prow = wp + n * 16 + lr;
                const short8 bfv = *(const short8*)(smem + 16384 +
                    ((prow * 256 + ks * 64 + lg * 16) ^ ((prow & 7) << 4)));
                acc[0][n] = __builtin_amdgcn_mfma_f32_16x16x32_bf16(af[0], bfv, acc[0][n], 0, 0, 0);
                acc[1][n] = __builtin_amdgcn_mfma_f32_16x16x32_bf16(af[1], bfv, acc[1][n], 0, 0, 0);
            }
        }
    }
    __syncthreads();

    float sv[2][4], tv[2][4];
#pragma unroll
    for (int m = 0; m < 2; ++m)
#pragma unroll
        for (int j = 0; j < 4; ++j) {
            const int ol = wo + m * 16 + 4 * lg + j;
            sv[m][j] = sArr[ol];
            tv[m][j] = tArr[ol];
        }
#pragma unroll
    for (int m = 0; m < 2; ++m)
#pragma unroll
        for (int n = 0; n < 4; ++n)
#pragma unroll
            for (int j = 0; j < 4; ++j) {
                const int ol = wo + m * 16 + 4 * lg + j;
                const int pl = wp + n * 16 + lr;
                const float val = fmaf(acc[m][n][j], sv[m][j], tv[m][j]);
                Df[ol * 130 + pl] = fmaxf(val, 0.f);
            }
    __syncthreads();

#pragma unroll
    for (int i = 0; i < 8; ++i) {
        const int oi = i * 256 + t;
        const int o  = oi >> 5;
        const int q  = oi & 31;
        const int prl = q >> 4;
        const int pc  = q & 15;
        const float a0 = Df[o * 130 + prl * 64 + 2 * pc];
        const float a1 = Df[o * 130 + prl * 64 + 2 * pc + 1];
        const float b0 = Df[o * 130 + prl * 64 + 32 + 2 * pc];
        const float b1 = Df[o * 130 + prl * 64 + 32 + 2 * pc + 1];
        xout[(((size_t)(b * 256 + o0 + o)) * 16 + 2 * blockIdx.y + prl) * 16 + pc] =
            fmaxf(fmaxf(a0, a1), fmaxf(b0, b1));
    }
}

// ---------------------------------------------------------------------------
// cat via bf16 MFMA: spikes[b,m,p] = sum_c x[b,c,p]*cw[m,c], m tile 32,
// full P=256 per block, K=256 as 4 x BK=64. catsum block-local.
// ---------------------------------------------------------------------------
__global__ __launch_bounds__(256) void cat_mfma(
    const float* __restrict__ x, const float* __restrict__ cw,
    float* __restrict__ spikes, float* __restrict__ catsum)
{
    __shared__ __align__(16) char smem[36864];
    __shared__ float cs[4][32];

    const int m0 = blockIdx.x * 32;
    const int b  = blockIdx.y;
    const int t  = threadIdx.x;

    const int lane = t & 63, wid = t >> 6;
    const int lr = lane & 15, lg = lane >> 4;
    const int wp = wid * 64;

    f32x4 acc[2][4];
#pragma unroll
    for (int m = 0; m < 2; ++m)
#pragma unroll
        for (int n = 0; n < 4; ++n) acc[m][n] = (f32x4){0.f, 0.f, 0.f, 0.f};

    const float* xb = x + (size_t)b * 65536;

#pragma unroll
    for (int ks = 0; ks < 4; ++ks) {
        if (ks) __syncthreads();

#pragma unroll
        for (int i = 0; i < 2; ++i) {
            const int li = i * 256 + t;
            const int ml = li >> 4;
            const int f4 = li & 15;
            const float4 wv = *(const float4*)(cw + (size_t)(m0 + ml) * 256 + ks * 64 + 4 * f4);
            ushort4 h;
            h.x = f2bf(wv.x); h.y = f2bf(wv.y); h.z = f2bf(wv.z); h.w = f2bf(wv.w);
            *(ushort4*)(smem + ((ml * 128 + f4 * 8) ^ ((ml & 7) << 4))) = h;
        }

#pragma unroll
        for (int i = 0; i < 4; ++i) {
            const int li = i * 256 + t;
            const int c4 = li >> 6;
            const int f4 = li & 63;
            float4 v0 = *(const float4*)(xb + (size_t)(ks * 64 + 4 * c4 + 0) * 256 + 4 * f4);
            float4 v1 = *(const float4*)(xb + (size_t)(ks * 64 + 4 * c4 + 1) * 256 + 4 * f4);
            float4 v2 = *(const float4*)(xb + (size_t)(ks * 64 + 4 * c4 + 2) * 256 + 4 * f4);
            float4 v3 = *(const float4*)(xb + (size_t)(ks * 64 + 4 * c4 + 3) * 256 + 4 * f4);
            ushort4 h0, h1, h2, h3;
            h0.x = f2bf(v0.x); h0.y = f2bf(v1.x); h0.z = f2bf(v2.x); h0.w = f2bf(v3.x);
            h1.x = f2bf(v0.y); h1.y = f2bf(v1.y); h1.z = f2bf(v2.y); h1.w = f2bf(v3.y);
            h2.x = f2bf(v0.z); h2.y = f2bf(v1.z); h2.z = f2bf(v2.z); h2.w = f2bf(v3.z);
            h3.x = f2bf(v0.w); h3.y = f2bf(v1.w); h3.z = f2bf(v2.w); h3.w = f2bf(v3.w);
            const int p_0 = 4 * f4;
            *(ushort4*)(smem + 4096 + (((p_0 + 0) * 128 + 8 * c4) ^ (((p_0 + 0) & 7) << 4))) = h0;
            *(ushort4*)(smem + 4096 + (((p_0 + 1) * 128 + 8 * c4) ^ (((p_0 + 1) & 7) << 4))) = h1;
            *(ushort4*)(smem + 4096 + (((p_0 + 2) * 128 + 8 * c4) ^ (((p_0 + 2) & 7) << 4))) = h2;
            *(ushort4*)(smem + 4096 + (((p_0 + 3) * 128 + 8 * c4) ^ (((p_0 + 3) & 7) << 4))) = h3;
        }
        __syncthreads();

#pragma unroll
        for (int kk = 0; kk < 2; ++kk) {
            short8 af[2];
#pragma unroll
            for (int m = 0; m < 2; ++m) {
                const int rowm = m * 16 + lr;
                af[m] = *(const short8*)(smem + ((rowm * 128 + kk * 64 + lg * 16) ^ ((rowm & 7) << 4)));
            }
#pragma unroll
            for (int n = 0; n < 4; ++n) {
                const int prow = wp + n * 16 + lr;
                const short8 bfv = *(const short8*)(smem + 4096 +
                    ((prow * 128 + kk * 64 + lg * 16) ^ ((prow & 7) << 4)));
                acc[0][n] = __builtin_amdgcn_mfma_f32_16x16x32_bf16(af[0], bfv, acc[0][n], 0, 0, 0);
                acc[1][n] = __builtin_amdgcn_mfma_f32_16x16x32_bf16(af[1], bfv, acc[1][n], 0, 0, 0);
            }
        }
    }

#pragma unroll
    for (int mi = 0; mi < 2; ++mi) {
#pragma unroll
        for (int j = 0; j < 4; ++j) {
            const int m = m0 + mi * 16 + 4 * lg + j;
#pragma unroll
            for (int n = 0; n < 4; ++n)
                spikes[((size_t)(b * 256 + m)) * 256 + wp + n * 16 + lr] = acc[mi][n][j];
            float s = acc[mi][0][j] + acc[mi][1][j] + acc[mi][2][j] + acc[mi][3][j];
            s += __shfl_xor(s, 1, 64);
            s += __shfl_xor(s, 2, 64);
            s += __shfl_xor(s, 4, 64);
            s += __shfl_xor(s, 8, 64);
            if (lr == 0) cs[wid][mi * 16 + 4 * lg + j] = s;
        }
    }
    __syncthreads();
    if (t < 32)
        catsum[b * 256 + m0 + t] = cs[0][t] + cs[1][t] + cs[2][t] + cs[3][t];
}

// ---------------------------------------------------------------------------
// final: pooled mean over pixels, embedding GEMV, category activations.
// ---------------------------------------------------------------------------
__global__ __launch_bounds__(256) void final_kernel(
    const float* __restrict__ x, const float* __restrict__ catsum,
    const float* __restrict__ embw, const float* __restrict__ embb,
    float* __restrict__ cat_act, float* __restrict__ emb)
{
    const int b = blockIdx.x;
    const int t = threadIdx.x;
    __shared__ __align__(16) float pooled[256];

    {
        const float4* src = (const float4*)(x + (size_t)b * 65536 + (size_t)t * 256);
        float s = 0.f;
#pragma unroll 8
        for (int i = 0; i < 64; ++i) {
            const float4 v = src[i];
            s += v.x + v.y + v.z + v.w;
        }
        pooled[t] = s * (1.0f / 256.0f);
    }
    __syncthreads();

    if (t < 128) {
        const float4* wr = (const float4*)(embw + (size_t)t * 256);
        float d = 0.f;
#pragma unroll 8
        for (int i = 0; i < 64; ++i) {
            const float4 wv = wr[i];
            const float4 pv = *(const float4*)&pooled[4 * i];
            d = fmaf(wv.x, pv.x, d);
            d = fmaf(wv.y, pv.y, d);
            d = fmaf(wv.z, pv.z, d);
            d = fmaf(wv.w, pv.w, d);
        }
        emb[b * 128 + t] = d + embb[t];
    } else if (t < 160) {
        const int k = t - 128;
        float s = 0.f;
#pragma unroll
        for (int o = 0; o < 8; ++o) s += catsum[b * 256 + k * 8 + o];
        cat_act[b * 32 + k] = s * (1.0f / 2048.0f);
    }
}

// ---------------------------------------------------------------------------
extern "C" void kernel_launch(void* const* d_in, const int* in_sizes, int n_in,
                              void* d_out, int out_size, void* d_ws, size_t ws_size,
                              hipStream_t stream) {
    const float* v4   = (const float*)d_in[0];
    const float* w1dw = (const float*)d_in[1];
    const float* w1pw = (const float*)d_in[2];
    const float* bn1g = (const float*)d_in[3];
    const float* bn1b = (const float*)d_in[4];
    const float* bn1m = (const float*)d_in[5];
    const float* bn1v = (const float*)d_in[6];
    const float* w2dw = (const float*)d_in[7];
    const float* w2pw = (const float*)d_in[8];
    const float* bn2g = (const float*)d_in[9];
    const float* bn2b = (const float*)d_in[10];
    const float* bn2m = (const float*)d_in[11];
    const float* bn2v = (const float*)d_in[12];
    const float* catw = (const float*)d_in[13];
    const float* embw = (const float*)d_in[14];
    const float* embb = (const float*)d_in[15];

    float* out        = (float*)d_out;
    float* cat_spikes = out;                    // [32][256][256]
    float* cat_act    = out + 2097152;          // [32][32]
    float* emb        = out + 2098176;          // [32][128]
    float* xout       = out + 2102272;          // [32][256][256]

    char* ws = (char*)d_ws;
    float* t1     = (float*)ws;                            // 64 MB (reused as t3)
    float* t2     = (float*)(ws + 67108864);               // 33.5 MB
    float* catsum = (float*)(ws + 67108864 + 33554432);    // 32 KB

    // Block 1
    dw_shfl<64, 6, 1, 4, 127><<<4096, 256, 0, stream>>>(v4, w1dw, t1);
    pw1_mfma<<<dim3(4, 32, 32), 256, 0, stream>>>(t1, w1pw, bn1g, bn1b, bn1m, bn1v, t2);
    // Block 2 (t3 reuses t1's buffer)
    dw_shfl<32, 5, 4, 1, 255><<<2048, 256, 0, stream>>>(t2, w2dw, t1);
    pw2_mfma<<<dim3(4, 8, 32), 256, 0, stream>>>(t1, w2pw, bn2g, bn2b, bn2m, bn2v, xout);
    // Category contraction + pooled sums
    cat_mfma<<<dim3(8, 32), 256, 0, stream>>>(xout, catw, cat_spikes, catsum);
    // Final reductions
    final_kernel<<<32, 256, 0, stream>>>(xout, catsum, embw, embb, cat_act, emb);
}

// Round 7
// 111.149 us; speedup vs baseline: 2.9454x; 1.3481x over previous
//
#include <hip/hip_runtime.h>

#define BN_EPS 1e-5f

typedef float f32x4 __attribute__((ext_vector_type(4)));
typedef short short8 __attribute__((ext_vector_type(8)));
typedef unsigned short u16;

__device__ __forceinline__ u16 f2bf(float f) {
    unsigned u = __builtin_bit_cast(unsigned, f);
    unsigned r = (u + 0x7FFFu + ((u >> 16) & 1u)) >> 16;   // round-nearest-even
    return (u16)r;
}

// two-term XOR swizzle: uniform bank slots for strided stores AND row-serial reads
#define SWZ(row) ((((row) & 7) ^ (((row) >> 3) & 7)) << 4)

// ---------------------------------------------------------------------------
// Depthwise 3x3, SAME, lane-contiguous, bf16 output.
// ---------------------------------------------------------------------------
template<int HW, int LOGW, int NPL, int IPP, int CMASK>
__global__ __launch_bounds__(256) void dw_shfl(
    const float* __restrict__ in, const float* __restrict__ wts,
    u16* __restrict__ out)
{
    const int t   = threadIdx.x;
    const int LPR = HW / 4;
    const int wq  = t & (LPR - 1);
    const int w0  = wq * 4;
    const int rin = t >> (LOGW - 2);

    for (int pl = 0; pl < NPL; ++pl) {
        const int plane = blockIdx.x * NPL + pl;
        const int c     = plane & CMASK;
        float wt[9];
#pragma unroll
        for (int i = 0; i < 9; ++i) wt[i] = wts[c * 9 + i];
        const float* ip = in  + (size_t)plane * (HW * HW);
        u16*         op = out + (size_t)plane * (HW * HW);

#pragma unroll
        for (int it = 0; it < IPP; ++it) {
            const int h = it * (1024 / HW) + rin;
            const float* rp = ip + h * HW + w0;
            const float4 zero4 = make_float4(0.f, 0.f, 0.f, 0.f);
            const float4 vc = *(const float4*)rp;
            const float4 vt = (h > 0)      ? *(const float4*)(rp - HW) : zero4;
            const float4 vb = (h < HW - 1) ? *(const float4*)(rp + HW) : zero4;

            float lc = __shfl_up(vc.w, 1),  rc = __shfl_down(vc.x, 1);
            float lt = __shfl_up(vt.w, 1),  rt = __shfl_down(vt.x, 1);
            float lb = __shfl_up(vb.w, 1),  rb = __shfl_down(vb.x, 1);
            if (wq == 0)       { lc = 0.f; lt = 0.f; lb = 0.f; }
            if (wq == LPR - 1) { rc = 0.f; rt = 0.f; rb = 0.f; }

            float o0 = 0.f, o1 = 0.f, o2 = 0.f, o3 = 0.f;
            o0 = fmaf(lt,   wt[0], fmaf(vt.x, wt[1], fmaf(vt.y, wt[2], o0)));
            o1 = fmaf(vt.x, wt[0], fmaf(vt.y, wt[1], fmaf(vt.z, wt[2], o1)));
            o2 = fmaf(vt.y, wt[0], fmaf(vt.z, wt[1], fmaf(vt.w, wt[2], o2)));
            o3 = fmaf(vt.z, wt[0], fmaf(vt.w, wt[1], fmaf(rt,   wt[2], o3)));
            o0 = fmaf(lc,   wt[3], fmaf(vc.x, wt[4], fmaf(vc.y, wt[5], o0)));
            o1 = fmaf(vc.x, wt[3], fmaf(vc.y, wt[4], fmaf(vc.z, wt[5], o1)));
            o2 = fmaf(vc.y, wt[3], fmaf(vc.z, wt[4], fmaf(vc.w, wt[5], o2)));
            o3 = fmaf(vc.z, wt[3], fmaf(vc.w, wt[4], fmaf(rc,   wt[5], o3)));
            o0 = fmaf(lb,   wt[6], fmaf(vb.x, wt[7], fmaf(vb.y, wt[8], o0)));
            o1 = fmaf(vb.x, wt[6], fmaf(vb.y, wt[7], fmaf(vb.z, wt[8], o1)));
            o2 = fmaf(vb.y, wt[6], fmaf(vb.z, wt[7], fmaf(vb.w, wt[8], o2)));
            o3 = fmaf(vb.z, wt[6], fmaf(vb.w, wt[7], fmaf(rb,   wt[8], o3)));

            ushort4 st;
            st.x = f2bf(o0); st.y = f2bf(o1); st.z = f2bf(o2); st.w = f2bf(o3);
            *(ushort4*)(op + h * HW + w0) = st;
        }
    }
}

// ---------------------------------------------------------------------------
// pw1 via bf16 MFMA: 64o x 128px, K=128 resident, bf16 input (no convert).
// XCD-chunked 1D grid: 4 o-blocks sharing an X tile sit 8 ids apart.
// ---------------------------------------------------------------------------
__global__ __launch_bounds__(256) void pw1_mfma(
    const u16* __restrict__ t1b, const float* __restrict__ w,
    const float* __restrict__ bg, const float* __restrict__ bb,
    const float* __restrict__ bm, const float* __restrict__ bv,
    float* __restrict__ t2)
{
    __shared__ __align__(16) char smem[49664];
    float* sArr = (float*)(smem + 49152);
    float* tArr = (float*)(smem + 49408);
    float* Df   = (float*)smem;              // [64][130] f32 (reuses A+B)

    const int bid = blockIdx.x;
    const int o0  = ((bid >> 3) & 3) * 64;
    const int pxb = (bid >> 5) * 8 + (bid & 7);   // [0,1024)
    const int py  = pxb & 31;
    const int b   = pxb >> 5;
    const int p0  = py * 128;
    const int t   = threadIdx.x;

    // ---- stage A: W fp32 -> bf16 swz ----
#pragma unroll
    for (int i = 0; i < 8; ++i) {
        const int li = i * 256 + t;
        const int ol = li >> 5;
        const int f4 = li & 31;
        const float4 wv = *(const float4*)(w + (size_t)(o0 + ol) * 128 + 4 * f4);
        ushort4 h;
        h.x = f2bf(wv.x); h.y = f2bf(wv.y); h.z = f2bf(wv.z); h.w = f2bf(wv.w);
        *(ushort4*)(smem + ((ol * 256 + f4 * 8) ^ SWZ(ol))) = h;
    }

    // ---- stage B: bf16 8x8 register transpose, conflict-optimal stores ----
    {
        const u16* xb = t1b + ((size_t)b * 128) * 4096 + p0;
        const int pg = t & 15, cg = t >> 4;
        short8 vin[8];
#pragma unroll
        for (int j = 0; j < 8; ++j)
            vin[j] = *(const short8*)(xb + (size_t)(8 * cg + j) * 4096 + 8 * pg);
#pragma unroll
        for (int k = 0; k < 8; ++k) {
            short8 ov;
            ov[0] = vin[0][k]; ov[1] = vin[1][k]; ov[2] = vin[2][k]; ov[3] = vin[3][k];
            ov[4] = vin[4][k]; ov[5] = vin[5][k]; ov[6] = vin[6][k]; ov[7] = vin[7][k];
            const int row = 8 * pg + k;
            *(short8*)(smem + 16384 + ((row * 256 + cg * 16) ^ SWZ(row))) = ov;
        }
    }

    if (t < 64) {
        const int o = o0 + t;
        const float s = bg[o] * rsqrtf(bv[o] + BN_EPS);
        sArr[t] = s;
        tArr[t] = bb[o] - bm[o] * s;
    }
    __syncthreads();

    const int lane = t & 63, wid = t >> 6;
    const int lr = lane & 15, lg = lane >> 4;
    const int wo = (wid >> 1) * 32;
    const int wp = (wid & 1) * 64;

    f32x4 acc[2][4];
#pragma unroll
    for (int m = 0; m < 2; ++m)
#pragma unroll
        for (int n = 0; n < 4; ++n) acc[m][n] = (f32x4){0.f, 0.f, 0.f, 0.f};

#pragma unroll
    for (int ks = 0; ks < 4; ++ks) {
        short8 af[2];
#pragma unroll
        for (int m = 0; m < 2; ++m) {
            const int rowm = wo + m * 16 + lr;
            af[m] = *(const short8*)(smem + ((rowm * 256 + ks * 64 + lg * 16) ^ SWZ(rowm)));
        }
#pragma unroll
        for (int n = 0; n < 4; ++n) {
            const int prow = wp + n * 16 + lr;
            const short8 bfv = *(const short8*)(smem + 16384 +
                ((prow * 256 + ks * 64 + lg * 16) ^ SWZ(prow)));
            acc[0][n] = __builtin_amdgcn_mfma_f32_16x16x32_bf16(af[0], bfv, acc[0][n], 0, 0, 0);
            acc[1][n] = __builtin_amdgcn_mfma_f32_16x16x32_bf16(af[1], bfv, acc[1][n], 0, 0, 0);
        }
    }
    __syncthreads();

    float sv[2][4], tv[2][4];
#pragma unroll
    for (int m = 0; m < 2; ++m)
#pragma unroll
        for (int j = 0; j < 4; ++j) {
            const int ol = wo + m * 16 + 4 * lg + j;
            sv[m][j] = sArr[ol];
            tv[m][j] = tArr[ol];
        }
#pragma unroll
    for (int m = 0; m < 2; ++m)
#pragma unroll
        for (int n = 0; n < 4; ++n)
#pragma unroll
            for (int j = 0; j < 4; ++j) {
                const int ol = wo + m * 16 + 4 * lg + j;
                const int pl = wp + n * 16 + lr;
                const float val = fmaf(acc[m][n][j], sv[m][j], tv[m][j]);
                Df[ol * 130 + pl] = fmaxf(val, 0.f);
            }
    __syncthreads();

#pragma unroll
    for (int i = 0; i < 8; ++i) {
        const int oi  = i * 256 + t;
        const int o   = oi >> 5;
        const int wpx = oi & 31;
        const float a0 = Df[o * 130 + 2 * wpx];
        const float a1 = Df[o * 130 + 2 * wpx + 1];
        const float b0 = Df[o * 130 + 64 + 2 * wpx];
        const float b1 = Df[o * 130 + 64 + 2 * wpx + 1];
        t2[(((size_t)(b * 256 + o0 + o)) * 32 + py) * 32 + wpx] =
            fmaxf(fmaxf(a0, a1), fmaxf(b0, b1));
    }
}

// ---------------------------------------------------------------------------
// pw2 via bf16 MFMA: 64o x 128px, K=256 as 2 stages, bf16 input.
// ---------------------------------------------------------------------------
__global__ __launch_bounds__(256) void pw2_mfma(
    const u16* __restrict__ t3b, const float* __restrict__ w,
    const float* __restrict__ bg, const float* __restrict__ bb,
    const float* __restrict__ bm, const float* __restrict__ bv,
    float* __restrict__ xout)
{
    __shared__ __align__(16) char smem[49664];
    float* sArr = (float*)(smem + 49152);
    float* tArr = (float*)(smem + 49408);
    float* Df   = (float*)smem;

    const int bid = blockIdx.x;
    const int o0  = ((bid >> 3) & 3) * 64;
    const int pxb = (bid >> 5) * 8 + (bid & 7);   // [0,256)
    const int px  = pxb & 7;
    const int b   = pxb >> 3;
    const int p0  = px * 128;
    const int t   = threadIdx.x;

    const int lane = t & 63, wid = t >> 6;
    const int lr = lane & 15, lg = lane >> 4;
    const int wo = (wid >> 1) * 32;
    const int wp = (wid & 1) * 64;

    f32x4 acc[2][4];
#pragma unroll
    for (int m = 0; m < 2; ++m)
#pragma unroll
        for (int n = 0; n < 4; ++n) acc[m][n] = (f32x4){0.f, 0.f, 0.f, 0.f};

#pragma unroll
    for (int ko = 0; ko < 2; ++ko) {
        if (ko) __syncthreads();

#pragma unroll
        for (int i = 0; i < 8; ++i) {
            const int li = i * 256 + t;
            const int ol = li >> 5;
            const int f4 = li & 31;
            const float4 wv = *(const float4*)(w + (size_t)(o0 + ol) * 256 + ko * 128 + 4 * f4);
            ushort4 h;
            h.x = f2bf(wv.x); h.y = f2bf(wv.y); h.z = f2bf(wv.z); h.w = f2bf(wv.w);
            *(ushort4*)(smem + ((ol * 256 + f4 * 8) ^ SWZ(ol))) = h;
        }

        {
            const u16* xb = t3b + ((size_t)b * 256 + ko * 128) * 1024 + p0;
            const int pg = t & 15, cg = t >> 4;
            short8 vin[8];
#pragma unroll
            for (int j = 0; j < 8; ++j)
                vin[j] = *(const short8*)(xb + (size_t)(8 * cg + j) * 1024 + 8 * pg);
#pragma unroll
            for (int k = 0; k < 8; ++k) {
                short8 ov;
                ov[0] = vin[0][k]; ov[1] = vin[1][k]; ov[2] = vin[2][k]; ov[3] = vin[3][k];
                ov[4] = vin[4][k]; ov[5] = vin[5][k]; ov[6] = vin[6][k]; ov[7] = vin[7][k];
                const int row = 8 * pg + k;
                *(short8*)(smem + 16384 + ((row * 256 + cg * 16) ^ SWZ(row))) = ov;
            }
        }

        if (ko == 0 && t < 64) {
            const int o = o0 + t;
            const float s = bg[o] * rsqrtf(bv[o] + BN_EPS);
            sArr[t] = s;
            tArr[t] = bb[o] - bm[o] * s;
        }
        __syncthreads();

#pragma unroll
        for (int ks = 0; ks < 4; ++ks) {
            short8 af[2];
#pragma unroll
            for (int m = 0; m < 2; ++m) {
                const int rowm = wo + m * 16 + lr;
                af[m] = *(const short8*)(smem + ((rowm * 256 + ks * 64 + lg * 16) ^ SWZ(rowm)));
            }
#pragma unroll
            for (int n = 0; n < 4; ++n) {
                const int prow = wp + n * 16 + lr;
                const short8 bfv = *(const short8*)(smem + 16384 +
                    ((prow * 256 + ks * 64 + lg * 16) ^ SWZ(prow)));
                acc[0][n] = __builtin_amdgcn_mfma_f32_16x16x32_bf16(af[0], bfv, acc[0][n], 0, 0, 0);
                acc[1][n] = __builtin_amdgcn_mfma_f32_16x16x32_bf16(af[1], bfv, acc[1][n], 0, 0, 0);
            }
        }
    }
    __syncthreads();

    float sv[2][4], tv[2][4];
#pragma unroll
    for (int m = 0; m < 2; ++m)
#pragma unroll
        for (int j = 0; j < 4; ++j) {
            const int ol = wo + m * 16 + 4 * lg + j;
            sv[m][j] = sArr[ol];
            tv[m][j] = tArr[ol];
        }
#pragma unroll
    for (int m = 0; m < 2; ++m)
#pragma unroll
        for (int n = 0; n < 4; ++n)
#pragma unroll
            for (int j = 0; j < 4; ++j) {
                const int ol = wo + m * 16 + 4 * lg + j;
                const int pl = wp + n * 16 + lr;
                const float val = fmaf(acc[m][n][j], sv[m][j], tv[m][j]);
                Df[ol * 130 + pl] = fmaxf(val, 0.f);
            }
    __syncthreads();

#pragma unroll
    for (int i = 0; i < 8; ++i) {
        const int oi = i * 256 + t;
        const int o  = oi >> 5;
        const int q  = oi & 31;
        const int prl = q >> 4;
        const int pc  = q & 15;
        const float a0 = Df[o * 130 + prl * 64 + 2 * pc];
        const float a1 = Df[o * 130 + prl * 64 + 2 * pc + 1];
        const float b0 = Df[o * 130 + prl * 64 + 32 + 2 * pc];
        const float b1 = Df[o * 130 + prl * 64 + 32 + 2 * pc + 1];
        xout[(((size_t)(b * 256 + o0 + o)) * 16 + 2 * px + prl) * 16 + pc] =
            fmaxf(fmaxf(a0, a1), fmaxf(b0, b1));
    }
}

// ---------------------------------------------------------------------------
// cat via bf16 MFMA. 1D grid, b fast -> all m-blocks of a batch on one XCD.
// ---------------------------------------------------------------------------
__global__ __launch_bounds__(256) void cat_mfma(
    const float* __restrict__ x, const float* __restrict__ cw,
    float* __restrict__ spikes, float* __restrict__ catsum)
{
    __shared__ __align__(16) char smem[36864];
    __shared__ float cs[4][32];

    const int bid = blockIdx.x;
    const int b   = bid & 31;
    const int m0  = (bid >> 5) * 32;
    const int t   = threadIdx.x;

    const int lane = t & 63, wid = t >> 6;
    const int lr = lane & 15, lg = lane >> 4;
    const int wp = wid * 64;

    f32x4 acc[2][4];
#pragma unroll
    for (int m = 0; m < 2; ++m)
#pragma unroll
        for (int n = 0; n < 4; ++n) acc[m][n] = (f32x4){0.f, 0.f, 0.f, 0.f};

    const float* xb = x + (size_t)b * 65536;

#pragma unroll
    for (int ks = 0; ks < 4; ++ks) {
        if (ks) __syncthreads();

#pragma unroll
        for (int i = 0; i < 2; ++i) {
            const int li = i * 256 + t;
            const int ml = li >> 4;
            const int f4 = li & 15;
            const float4 wv = *(const float4*)(cw + (size_t)(m0 + ml) * 256 + ks * 64 + 4 * f4);
            ushort4 h;
            h.x = f2bf(wv.x); h.y = f2bf(wv.y); h.z = f2bf(wv.z); h.w = f2bf(wv.w);
            *(ushort4*)(smem + ((ml * 128 + f4 * 8) ^ SWZ(ml))) = h;
        }

#pragma unroll
        for (int i = 0; i < 4; ++i) {
            const int li = i * 256 + t;
            const int c4 = li >> 6;
            const int f4 = li & 63;
            float4 v0 = *(const float4*)(xb + (size_t)(ks * 64 + 4 * c4 + 0) * 256 + 4 * f4);
            float4 v1 = *(const float4*)(xb + (size_t)(ks * 64 + 4 * c4 + 1) * 256 + 4 * f4);
            float4 v2 = *(const float4*)(xb + (size_t)(ks * 64 + 4 * c4 + 2) * 256 + 4 * f4);
            float4 v3 = *(const float4*)(xb + (size_t)(ks * 64 + 4 * c4 + 3) * 256 + 4 * f4);
            ushort4 h0, h1, h2, h3;
            h0.x = f2bf(v0.x); h0.y = f2bf(v1.x); h0.z = f2bf(v2.x); h0.w = f2bf(v3.x);
            h1.x = f2bf(v0.y); h1.y = f2bf(v1.y); h1.z = f2bf(v2.y); h1.w = f2bf(v3.y);
            h2.x = f2bf(v0.z); h2.y = f2bf(v1.z); h2.z = f2bf(v2.z); h2.w = f2bf(v3.z);
            h3.x = f2bf(v0.w); h3.y = f2bf(v1.w); h3.z = f2bf(v2.w); h3.w = f2bf(v3.w);
            const int p_0 = 4 * f4;
            *(ushort4*)(smem + 4096 + (((p_0 + 0) * 128 + 8 * c4) ^ SWZ(p_0 + 0))) = h0;
            *(ushort4*)(smem + 4096 + (((p_0 + 1) * 128 + 8 * c4) ^ SWZ(p_0 + 1))) = h1;
            *(ushort4*)(smem + 4096 + (((p_0 + 2) * 128 + 8 * c4) ^ SWZ(p_0 + 2))) = h2;
            *(ushort4*)(smem + 4096 + (((p_0 + 3) * 128 + 8 * c4) ^ SWZ(p_0 + 3))) = h3;
        }
        __syncthreads();

#pragma unroll
        for (int kk = 0; kk < 2; ++kk) {
            short8 af[2];
#pragma unroll
            for (int m = 0; m < 2; ++m) {
                const int rowm = m * 16 + lr;
                af[m] = *(const short8*)(smem + ((rowm * 128 + kk * 64 + lg * 16) ^ SWZ(rowm)));
            }
#pragma unroll
            for (int n = 0; n < 4; ++n) {
                const int prow = wp + n * 16 + lr;
                const short8 bfv = *(const short8*)(smem + 4096 +
                    ((prow * 128 + kk * 64 + lg * 16) ^ SWZ(prow)));
                acc[0][n] = __builtin_amdgcn_mfma_f32_16x16x32_bf16(af[0], bfv, acc[0][n], 0, 0, 0);
                acc[1][n] = __builtin_amdgcn_mfma_f32_16x16x32_bf16(af[1], bfv, acc[1][n], 0, 0, 0);
            }
        }
    }

#pragma unroll
    for (int mi = 0; mi < 2; ++mi) {
#pragma unroll
        for (int j = 0; j < 4; ++j) {
            const int m = m0 + mi * 16 + 4 * lg + j;
#pragma unroll
            for (int n = 0; n < 4; ++n)
                spikes[((size_t)(b * 256 + m)) * 256 + wp + n * 16 + lr] = acc[mi][n][j];
            float s = acc[mi][0][j] + acc[mi][1][j] + acc[mi][2][j] + acc[mi][3][j];
            s += __shfl_xor(s, 1, 64);
            s += __shfl_xor(s, 2, 64);
            s += __shfl_xor(s, 4, 64);
            s += __shfl_xor(s, 8, 64);
            if (lr == 0) cs[wid][mi * 16 + 4 * lg + j] = s;
        }
    }
    __syncthreads();
    if (t < 32)
        catsum[b * 256 + m0 + t] = cs[0][t] + cs[1][t] + cs[2][t] + cs[3][t];
}

// ---------------------------------------------------------------------------
// final: pooled mean, embedding GEMV, category activations.
// ---------------------------------------------------------------------------
__global__ __launch_bounds__(256) void final_kernel(
    const float* __restrict__ x, const float* __restrict__ catsum,
    const float* __restrict__ embw, const float* __restrict__ embb,
    float* __restrict__ cat_act, float* __restrict__ emb)
{
    const int b = blockIdx.x;
    const int t = threadIdx.x;
    __shared__ __align__(16) float pooled[256];

    {
        const float4* src = (const float4*)(x + (size_t)b * 65536 + (size_t)t * 256);
        float s = 0.f;
#pragma unroll 8
        for (int i = 0; i < 64; ++i) {
            const float4 v = src[i];
            s += v.x + v.y + v.z + v.w;
        }
        pooled[t] = s * (1.0f / 256.0f);
    }
    __syncthreads();

    if (t < 128) {
        const float4* wr = (const float4*)(embw + (size_t)t * 256);
        float d = 0.f;
#pragma unroll 8
        for (int i = 0; i < 64; ++i) {
            const float4 wv = wr[i];
            const float4 pv = *(const float4*)&pooled[4 * i];
            d = fmaf(wv.x, pv.x, d);
            d = fmaf(wv.y, pv.y, d);
            d = fmaf(wv.z, pv.z, d);
            d = fmaf(wv.w, pv.w, d);
        }
        emb[b * 128 + t] = d + embb[t];
    } else if (t < 160) {
        const int k = t - 128;
        float s = 0.f;
#pragma unroll
        for (int o = 0; o < 8; ++o) s += catsum[b * 256 + k * 8 + o];
        cat_act[b * 32 + k] = s * (1.0f / 2048.0f);
    }
}

// ---------------------------------------------------------------------------
extern "C" void kernel_launch(void* const* d_in, const int* in_sizes, int n_in,
                              void* d_out, int out_size, void* d_ws, size_t ws_size,
                              hipStream_t stream) {
    const float* v4   = (const float*)d_in[0];
    const float* w1dw = (const float*)d_in[1];
    const float* w1pw = (const float*)d_in[2];
    const float* bn1g = (const float*)d_in[3];
    const float* bn1b = (const float*)d_in[4];
    const float* bn1m = (const float*)d_in[5];
    const float* bn1v = (const float*)d_in[6];
    const float* w2dw = (const float*)d_in[7];
    const float* w2pw = (const float*)d_in[8];
    const float* bn2g = (const float*)d_in[9];
    const float* bn2b = (const float*)d_in[10];
    const float* bn2m = (const float*)d_in[11];
    const float* bn2v = (const float*)d_in[12];
    const float* catw = (const float*)d_in[13];
    const float* embw = (const float*)d_in[14];
    const float* embb = (const float*)d_in[15];

    float* out        = (float*)d_out;
    float* cat_spikes = out;                    // [32][256][256]
    float* cat_act    = out + 2097152;          // [32][32]
    float* emb        = out + 2098176;          // [32][128]
    float* xout       = out + 2102272;          // [32][256][256]

    char* ws = (char*)d_ws;
    u16*   t1b    = (u16*)ws;                              // 32 MB bf16 (reused as t3b)
    float* t2     = (float*)(ws + 33554432);               // 33.5 MB fp32
    float* catsum = (float*)(ws + 33554432 + 33554432);    // 32 KB
    u16*   t3b    = (u16*)ws;                              // 16.75 MB bf16

    // Block 1
    dw_shfl<64, 6, 1, 4, 127><<<4096, 256, 0, stream>>>(v4, w1dw, t1b);
    pw1_mfma<<<4096, 256, 0, stream>>>(t1b, w1pw, bn1g, bn1b, bn1m, bn1v, t2);
    // Block 2
    dw_shfl<32, 5, 4, 1, 255><<<2048, 256, 0, stream>>>(t2, w2dw, t3b);
    pw2_mfma<<<1024, 256, 0, stream>>>(t3b, w2pw, bn2g, bn2b, bn2m, bn2v, xout);
    // Category contraction + pooled sums
    cat_mfma<<<256, 256, 0, stream>>>(xout, catw, cat_spikes, catsum);
    // Final reductions
    final_kernel<<<32, 256, 0, stream>>>(xout, catsum, embw, embb, cat_act, emb);
}